// Round 5
// baseline (643.805 us; speedup 1.0000x reference)
//
#include <hip/hip_runtime.h>
#include <hip/hip_bf16.h>
#include <math.h>

// LSD (local shape descriptors), 128^3, 8 labels, sigma=5, truncate=3 -> 31-tap kernel.
//
// Algebra: for label mask m, define G_{abc} = (k_a *_z)(k_b *_y)(k_c *_x) m with
//   k0(u)=w(u), k1(u)=u w(u), k2(u)=u^2 w(u)  (w = normalized gaussian).
// At a voxel with mass=G000>0, p=G100/mass, q=G010/mass, s=G001/mass:
//   mean_offset = 0.5 - {p,q,s}/(2 sigma);  cov_ab = (G../mass - ..)/sigma^2.
// Translation-invariant: coords input not needed. Masks disjoint.
//
// R8: SPARSE phase 2 (LDS list, bf16 B rows): 487 us.
// R9: label-adjacent order, no-memset, pipelines: 422 (L2 thrash on A).
// R10: bf16 A + tile-major: 412. FETCH 61 MB. NOT BW-bound: latency/issue.
// R11: 2-deep pipes + ballot compaction: 407 (pass_yx 289, VALU 46%, occ 21%).
// R12: one block owns tile across 8 labels, f16 LDS out-stage: 452 (pass_yx
//      333). Occ 21->44%, WRITE 468->82 MB -- skeleton works. BUT staging
//      layer added ~60 us of VALU (pack/readout) and 4M bank conflicts
//      (x-stride-4 list order). Lesson: write amp was never binding; don't
//      spend VALU to fix it.
// R13 (this round): keep R12 skeleton, drop the staging tax.
//   a) direct f32 scatter stores (R11-style) -- but compaction now iterates
//      wave-owned CONTIGUOUS 64-voxel spans (via 1KB seg_lds), so list
//      entries are x-consecutive: Bu reads conflict-free, stores coalesce
//      into contiguous runs, all 8 labels hit the same 40KB out-footprint
//      within one block lifetime -> L2 merges lines.
//   b) LDS 37.9 -> 18.2 KB: 8 blocks/CU x 4 waves = 32 waves/CU cap.
//      __launch_bounds__(256,8) to hold VGPR <= 64.
//   c) keep: per-label loop with phase1(l+1) || phase2(l) overlap, ballot
//      compaction, kq4 b128 weights, zero-designation (v&7)+1, no memset.

constexpr int NV = 128 * 128 * 128;
constexpr int SLICE = 128 * 128;
constexpr int R = 15;
constexpr int KL = 31;
constexpr int CSTRIDE = 160;            // u16: 16 pad + 128 data + 16 pad
constexpr int RSTRIDE = 6 * CSTRIDE + 8; // 968 u16; row stagger
constexpr int LCAP = 512;

struct Kw { float k0[KL]; float k1[KL]; float k2[KL]; };

__device__ __forceinline__ void fma4(float4& a, float w, const float4& b) {
    a.x = fmaf(w, b.x, a.x); a.y = fmaf(w, b.y, a.y);
    a.z = fmaf(w, b.z, a.z); a.w = fmaf(w, b.w, a.w);
}

__device__ __forceinline__ float4 load_mask4(const unsigned char* p, int lab) {
    unsigned int u = *(const unsigned int*)p;
    return make_float4(((u       ) & 255u) == (unsigned)lab ? 1.f : 0.f,
                       ((u >>  8 ) & 255u) == (unsigned)lab ? 1.f : 0.f,
                       ((u >> 16 ) & 255u) == (unsigned)lab ? 1.f : 0.f,
                       ((u >> 24 ) & 255u) == (unsigned)lab ? 1.f : 0.f);
}
__device__ __forceinline__ float4 load_mask4(const int* p, int lab) {
    int4 s = *(const int4*)p;
    return make_float4(s.x == lab ? 1.f : 0.f, s.y == lab ? 1.f : 0.f,
                       s.z == lab ? 1.f : 0.f, s.w == lab ? 1.f : 0.f);
}

__device__ __forceinline__ unsigned seg_pack4(const unsigned char* p) {
    return *(const unsigned int*)p;
}
__device__ __forceinline__ unsigned seg_pack4(const int* p) {
    int4 v = *(const int4*)p;
    return (unsigned)(v.x & 255) | ((unsigned)(v.y & 255) << 8) |
           ((unsigned)(v.z & 255) << 16) | ((unsigned)(v.w & 255) << 24);
}

__device__ __forceinline__ float bf_ld(const unsigned short* p) {
    return __uint_as_float(((unsigned int)(*p)) << 16);
}

// 4 packed bf16 (as uint2) -> float4. 1 VALU op per value.
__device__ __forceinline__ float4 bf4_to_f4(uint2 u) {
    return make_float4(__uint_as_float(u.x << 16),
                       __uint_as_float(u.x & 0xFFFF0000u),
                       __uint_as_float(u.y << 16),
                       __uint_as_float(u.y & 0xFFFF0000u));
}

__device__ __forceinline__ unsigned pack_bf2(float a, float b) {
    __hip_bfloat162 h = __float22bfloat162_rn(make_float2(a, b));
    return *reinterpret_cast<unsigned*>(&h);
}

// -------- pass_z: seg -> A[lab][3] bf16 (z-conv). grid (512, nlab), 256 thr.
template <typename ST>
__global__ __launch_bounds__(256) void pass_z_t(const ST* __restrict__ seg,
                                                unsigned short* __restrict__ A,
                                                int label0, size_t a_stride,
                                                Kw kw) {
    __shared__ float kp[3][37];           // zero-padded: kp[c][i] = k_c[i-3]
    if (threadIdx.x < 37) {
        int i = threadIdx.x, j = i - 3; bool ok = (j >= 0) && (j < KL);
        kp[0][i] = ok ? kw.k0[j] : 0.f;
        kp[1][i] = ok ? kw.k1[j] : 0.f;
        kp[2][i] = ok ? kw.k2[j] : 0.f;
    }
    __syncthreads();
    const int label = label0 + blockIdx.y;
    unsigned short* Ab = A + (size_t)blockIdx.y * a_stride;
    const int h = blockIdx.x, g = h & 7, l = h >> 3;       // 512 x-blocks
    const int tx = threadIdx.x & 31, ty = threadIdx.x >> 5;
    const int x0 = tx * 4;
    const int z0 = 16 * g + 4 * (l & 3);                   // XCD g owns z [16g,16g+16)
    const int y  = (l >> 2) * 8 + ty;

    float4 acc[4][3];
#pragma unroll
    for (int t = 0; t < 4; ++t)
#pragma unroll
        for (int c = 0; c < 3; ++c) acc[t][c] = make_float4(0.f, 0.f, 0.f, 0.f);

    // 2-deep pipelined sliding window: load j+2 while FMAing j.
    float4 cm = make_float4(0.f, 0.f, 0.f, 0.f), nm = cm;
    {
        int zz = z0 - R;
        if ((unsigned)zz < 128u)
            cm = load_mask4(seg + (zz * SLICE + y * 128 + x0), label);
        int zn = z0 + 1 - R;
        if ((unsigned)zn < 128u)
            nm = load_mask4(seg + (zn * SLICE + y * 128 + x0), label);
    }
    for (int j = 0; j < 34; ++j) {                         // window: 4 outs + 30
        float4 fm = make_float4(0.f, 0.f, 0.f, 0.f);
        int zz = z0 + j + 2 - R;                           // uniform per wave
        if (j < 32 && (unsigned)zz < 128u)
            fm = load_mask4(seg + (zz * SLICE + y * 128 + x0), label);
#pragma unroll
        for (int t = 0; t < 4; ++t) {
            int i = j - t + 3;                             // padded weight index
            fma4(acc[t][0], kp[0][i], cm);
            fma4(acc[t][1], kp[1][i], cm);
            fma4(acc[t][2], kp[2][i], cm);
        }
        cm = nm; nm = fm;
    }
#pragma unroll
    for (int t = 0; t < 4; ++t) {
        int base = (z0 + t) * SLICE + y * 128 + x0;
#pragma unroll
        for (int c = 0; c < 3; ++c) {
            float4 v = acc[t][c];
            uint2 pv = make_uint2(pack_bf2(v.x, v.y), pack_bf2(v.z, v.w));
            *reinterpret_cast<uint2*>(Ab + (size_t)c * NV + base) = pv;
        }
    }
}

// ---- per-voxel sparse x-conv (B rows in bf16 LDS, zero-padded) ----
__device__ __forceinline__ void conv_voxel(const unsigned short* __restrict__ Bu,
                                           int rr, int x, const Kw& kw,
                                           float o[10]) {
    const unsigned short* row = Bu + rr * RSTRIDE + (x + 1);
    float g000 = 0, g001 = 0, g002 = 0, g010 = 0, g011 = 0,
          g020 = 0, g100 = 0, g101 = 0, g110 = 0, g200 = 0;
#pragma unroll
    for (int j = 0; j < KL; ++j) {
        float w0 = kw.k0[j], w1 = kw.k1[j], w2 = kw.k2[j];
        float b0 = bf_ld(row + 0 * CSTRIDE + j);
        float b1 = bf_ld(row + 1 * CSTRIDE + j);
        float b2 = bf_ld(row + 2 * CSTRIDE + j);
        float b3 = bf_ld(row + 3 * CSTRIDE + j);
        float b4 = bf_ld(row + 4 * CSTRIDE + j);
        float b5 = bf_ld(row + 5 * CSTRIDE + j);
        g000 = fmaf(w0, b0, g000); g001 = fmaf(w1, b0, g001); g002 = fmaf(w2, b0, g002);
        g010 = fmaf(w0, b1, g010); g011 = fmaf(w1, b1, g011);
        g020 = fmaf(w0, b2, g020);
        g100 = fmaf(w0, b3, g100); g101 = fmaf(w1, b3, g101);
        g110 = fmaf(w0, b4, g110);
        g200 = fmaf(w0, b5, g200);
    }
    float mass = g000;
    float denom = (mass > 0.f) ? mass : 1.f;
    float inv = 1.f / denom;
    float p = g100 * inv, q = g010 * inv, s = g001 * inv;
    const float cs = 1.0f / 25.0f;                         // 1/sigma^2
    o[0] = 0.5f - 0.1f * p;                                // 1/(2 sigma) = 0.1
    o[1] = 0.5f - 0.1f * q;
    o[2] = 0.5f - 0.1f * s;
    o[3] = (g200 * inv - p * p) * cs;
    o[4] = (g020 * inv - q * q) * cs;
    o[5] = (g002 * inv - s * s) * cs;
    o[6] = (g110 * inv - p * q) * cs;
    o[7] = (g011 * inv - q * s) * cs;
    o[8] = (g101 * inv - p * s) * cs;
    o[9] = mass;
#pragma unroll
    for (int c = 0; c < 10; ++c) o[c] = fminf(fmaxf(o[c], 0.f), 1.f);
}

__device__ __forceinline__ void do_voxel_out(const unsigned short* __restrict__ Bu,
                                             int rr, int x, int z0, int y0,
                                             float* __restrict__ out, const Kw& kw) {
    float o[10];
    conv_voxel(Bu, rr, x, kw, o);
    const int z2 = z0 + (rr >> 2), y2 = y0 + (rr & 3);
    const int v = (z2 * 128 + y2) * 128 + x;
#pragma unroll
    for (int c = 0; c < 10; ++c) out[(size_t)c * NV + v] = o[c];
}

__device__ __forceinline__ void zero_voxel(int rr, int x, int z0, int y0,
                                           float* __restrict__ out) {
    const int z2 = z0 + (rr >> 2), y2 = y0 + (rr & 3);
    const int v = (z2 * 128 + y2) * 128 + x;
#pragma unroll
    for (int c = 0; c < 10; ++c) out[(size_t)c * NV + v] = 0.f;
}

// -------- pass_yx_all: A[8][3] bf16 -> out. grid (2048), 256 thr. ----------
// One block = one 8-row tile (2z x 4y x 128x), loops over all 8 labels.
// Per label: phase 1 (4 waves = 2 z-rows x 2 channel-groups) -> Bu bf16;
// ballot compaction over contiguous wave-owned 64-voxel spans (x-consecutive
// list); sparse phase 2 writes f32 descriptors (and zeros) direct to out.
template <typename ST>
__global__ __launch_bounds__(256, 8) void pass_yx_all(
        const unsigned short* __restrict__ A,
        const ST* __restrict__ seg,
        float* __restrict__ out,
        size_t a_stride, Kw kw) {
    __shared__ float4 kq4[40];                              // {k0,k1,k2,0}[i-3]
    __shared__ __align__(16) unsigned short Bu[8 * RSTRIDE];   // 15,488 B
    __shared__ unsigned seg_l[256];                            // tile seg bytes, 1 KB
    __shared__ unsigned short lst[LCAP];                       // 1 KB
    __shared__ int cnt2[2];

    // init: zero Bu (pads must be 0), weights, counters, seg_lds
    {
        uint4 z4 = make_uint4(0, 0, 0, 0);
        uint4* b4 = (uint4*)Bu;                            // 8*968/8 = 968
        for (int i = threadIdx.x; i < 968; i += 256) b4[i] = z4;
    }
    if (threadIdx.x < 40) {
        int i = threadIdx.x, j = i - 3; bool ok = (j >= 0) && (j < KL);
        kq4[i] = make_float4(ok ? kw.k0[j] : 0.f, ok ? kw.k1[j] : 0.f,
                             ok ? kw.k2[j] : 0.f, 0.f);
    }
    if (threadIdx.x == 0) { cnt2[0] = 0; cnt2[1] = 0; }

    const int b = blockIdx.x, g = b & 7, l = b >> 3;       // 2048 tiles
    const int z0 = 16 * g + 2 * (l & 7);                   // XCD g owns z slab
    const int y0 = (l >> 3) * 4;                           // 32 y-tiles

    // seg for this tile, once: thread t owns voxels 4t..4t+3 (v = rr*128+x)
    const unsigned pk = seg_pack4(seg +
        ((z0 + (threadIdx.x >> 7)) * 128 + (y0 + ((threadIdx.x >> 5) & 3))) * 128 +
        (threadIdx.x & 31) * 4);
    seg_l[threadIdx.x] = pk;

    // phase-1 wave roles
    const int w = threadIdx.x >> 6;
    const int zr = w & 1, cg = w >> 1;                     // z-row, channel group
    const int lane = threadIdx.x & 63;
    const int lx = lane & 31, lh = lane >> 5;
    const int x0 = 4 * lx;                                 // u16 elements
    const int t0 = 2 * lh;                                 // this half-wave's y-outs
    const int zrs = (z0 + zr) * SLICE;
    const unsigned long long below_mask = (1ull << lane) - 1ull;

    __syncthreads();

    for (int labi = 0; labi < 8; ++labi) {
        const int label = 1 + labi;
        const unsigned short* Ab0 = A + (size_t)labi * a_stride;
        const unsigned short* Ab1 = Ab0 + NV;
        const unsigned short* Ab2 = Ab0 + 2 * NV;

        // ---- phase 1: y-conv into registers (overlaps prev label's phase 2
        //      on other waves; touches no mutable shared state) ----
        float4 acc[3][2];
#pragma unroll
        for (int c = 0; c < 3; ++c)
#pragma unroll
            for (int k = 0; k < 2; ++k) acc[c][k] = make_float4(0.f, 0.f, 0.f, 0.f);

        uint2 u0c = make_uint2(0u, 0u), u0n = u0c;
        uint2 u1c = u0c, u1n = u0c, u2c = u0c, u2n = u0c;
        {
            int yy = y0 - R;
            if ((unsigned)yy < 128u) {
                int base = zrs + yy * 128 + x0;
                if (cg == 0) u0c = *(const uint2*)(Ab0 + base);
                else { u1c = *(const uint2*)(Ab1 + base); u2c = *(const uint2*)(Ab2 + base); }
            }
            int yn = y0 + 1 - R;
            if ((unsigned)yn < 128u) {
                int base = zrs + yn * 128 + x0;
                if (cg == 0) u0n = *(const uint2*)(Ab0 + base);
                else { u1n = *(const uint2*)(Ab1 + base); u2n = *(const uint2*)(Ab2 + base); }
            }
        }
        for (int j = 0; j < 34; ++j) {
            uint2 f0 = make_uint2(0u, 0u), f1 = f0, f2 = f0;
            int yy = y0 + j + 2 - R;
            if (j < 32 && (unsigned)yy < 128u) {
                int base = zrs + yy * 128 + x0;
                if (cg == 0) f0 = *(const uint2*)(Ab0 + base);
                else { f1 = *(const uint2*)(Ab1 + base); f2 = *(const uint2*)(Ab2 + base); }
            }
            if (cg == 0) {
                float4 a0 = bf4_to_f4(u0c);
#pragma unroll
                for (int k = 0; k < 2; ++k) {
                    float4 wv = kq4[j + 3 - (t0 + k)];
                    fma4(acc[0][k], wv.x, a0);
                    fma4(acc[1][k], wv.y, a0);
                    fma4(acc[2][k], wv.z, a0);
                }
            } else {
                float4 a1 = bf4_to_f4(u1c), a2 = bf4_to_f4(u2c);
#pragma unroll
                for (int k = 0; k < 2; ++k) {
                    float4 wv = kq4[j + 3 - (t0 + k)];
                    fma4(acc[0][k], wv.x, a1);
                    fma4(acc[1][k], wv.y, a1);
                    fma4(acc[2][k], wv.x, a2);
                }
            }
            u0c = u0n; u1c = u1n; u2c = u2n;
            u0n = f0;  u1n = f1;  u2n = f2;
        }

        __syncthreads();   // prev label's phase 2 done reading Bu/lst/cnt

        // ---- epilogue: write Bu; compact this label's voxels ----
#pragma unroll
        for (int k = 0; k < 2; ++k) {
            const int row = zr * 4 + t0 + k;
#pragma unroll
            for (int c3 = 0; c3 < 3; ++c3) {
                const int c = cg * 3 + c3;
                float4 v = acc[c3][k];
                uint2 pv = make_uint2(pack_bf2(v.x, v.y), pack_bf2(v.z, v.w));
                *reinterpret_cast<uint2*>(Bu + row * RSTRIDE + c * CSTRIDE + 16 + x0) = pv;
            }
        }
        {
            int* cw = &cnt2[labi & 1];
            const unsigned char* s8 = (const unsigned char*)seg_l;
#pragma unroll
            for (int s = 0; s < 4; ++s) {
                const int v = (w << 8) + (s << 6) + lane;  // contiguous span
                const int sv = (int)s8[v];
                const bool mt = (sv == label);
                const bool zt = !mt && (sv < 1 || sv > 8) &&
                                (((v & 7) + 1) == label);
                const bool pred = mt | zt;
                unsigned long long bal = __ballot(pred);
                int base = 0;
                if (lane == 0 && bal) base = atomicAdd(cw, (int)__popcll(bal));
                base = __shfl(base, 0);
                if (pred) {
                    int pos = base + (int)__popcll(bal & below_mask);
                    if (pos < LCAP)
                        lst[pos] = (unsigned short)(v | (zt ? 0x8000 : 0));
                }
            }
            if (threadIdx.x == 0) cnt2[(labi + 1) & 1] = 0;
        }

        __syncthreads();   // Bu + lst + cnt visible

        // ---- phase 2: sparse x-conv + direct f32 stores ----
        const int total = cnt2[labi & 1];
        if (total <= LCAP) {
            for (int e = threadIdx.x; e < total; e += 256) {
                int ent = lst[e];
                int v = ent & 1023, rr = v >> 7, x = v & 127;
                const int gb = ((z0 + (rr >> 2)) * 128 + (y0 + (rr & 3))) * 128 + x;
                if (ent & 0x8000) {
#pragma unroll
                    for (int c = 0; c < 10; ++c) out[(size_t)c * NV + gb] = 0.f;
                } else {
                    float o[10];
                    conv_voxel(Bu, rr, x, kw, o);
#pragma unroll
                    for (int c = 0; c < 10; ++c) out[(size_t)c * NV + gb] = o[c];
                }
            }
        } else {
            // adversarial-density fallback: each thread sweeps its 4 voxels
#pragma unroll
            for (int t = 0; t < 4; ++t) {
                const int sv = (int)((pk >> (8 * t)) & 255u);
                const int v = 4 * (int)threadIdx.x + t;
                const int rr = v >> 7, x = v & 127;
                const int gb = ((z0 + (rr >> 2)) * 128 + (y0 + (rr & 3))) * 128 + x;
                if (sv == label) {
                    float o[10];
                    conv_voxel(Bu, rr, x, kw, o);
#pragma unroll
                    for (int c = 0; c < 10; ++c) out[(size_t)c * NV + gb] = o[c];
                } else if ((sv < 1 || sv > 8) && (((v & 7) + 1) == label)) {
#pragma unroll
                    for (int c = 0; c < 10; ++c) out[(size_t)c * NV + gb] = 0.f;
                }
            }
        }
    }
}

// -------- fallback pass_yx (per-label, scatter writes) — R11 version ------
template <typename ST>
__global__ __launch_bounds__(128) void pass_yx(const unsigned short* __restrict__ A,
                                               const ST* __restrict__ seg,
                                               float* __restrict__ out,
                                               int label0, size_t a_stride,
                                               Kw kw) {
    __shared__ float kp[3][37];
    __shared__ __align__(16) unsigned short Bu2[16 * RSTRIDE];
    __shared__ unsigned short lst[LCAP];
    __shared__ int cnt;

    {
        uint4 z4 = make_uint4(0, 0, 0, 0);
        uint4* b4 = (uint4*)Bu2;
        for (int i = threadIdx.x; i < 1936; i += 128) b4[i] = z4;
    }
    if (threadIdx.x < 37) {
        int i = threadIdx.x, j = i - 3; bool ok = (j >= 0) && (j < KL);
        kp[0][i] = ok ? kw.k0[j] : 0.f;
        kp[1][i] = ok ? kw.k1[j] : 0.f;
        kp[2][i] = ok ? kw.k2[j] : 0.f;
    }
    if (threadIdx.x == 0) cnt = 0;
    __syncthreads();

    const int labi = blockIdx.y;
    const int label = label0 + labi;
    const unsigned short* Ab = A + (size_t)labi * a_stride;
    const int h = blockIdx.x, g = h & 7, l = h >> 3;
    const int tx = threadIdx.x & 31, tz = threadIdx.x >> 5;
    const int x0 = tx * 4;
    const int z0 = 16 * g + 4 * (l & 3);
    const int y0 = (l >> 2) * 4;
    const int zs = (z0 + tz) * SLICE;

    const int rr_c = threadIdx.x >> 3, q0_c = threadIdx.x & 7;
    const int vrow_c = ((z0 + (rr_c >> 2)) * 128 + (y0 + (rr_c & 3))) * 128;
    unsigned pk[4];
#pragma unroll
    for (int k = 0; k < 4; ++k)
        pk[k] = seg_pack4(seg + vrow_c + 4 * (q0_c + 8 * k));

    float4 acc[6][4];
#pragma unroll
    for (int c = 0; c < 6; ++c)
#pragma unroll
        for (int t = 0; t < 4; ++t) acc[c][t] = make_float4(0.f, 0.f, 0.f, 0.f);

    uint2 c0 = make_uint2(0u, 0u), c1 = c0, c2 = c0;
    uint2 n0 = c0, n1 = c0, n2 = c0;
    {
        int yy = y0 - R;
        if ((unsigned)yy < 128u) {
            int base = zs + yy * 128 + x0;
            c0 = *(const uint2*)(Ab + base);
            c1 = *(const uint2*)(Ab + NV + base);
            c2 = *(const uint2*)(Ab + 2 * NV + base);
        }
        int yn = y0 + 1 - R;
        if ((unsigned)yn < 128u) {
            int base = zs + yn * 128 + x0;
            n0 = *(const uint2*)(Ab + base);
            n1 = *(const uint2*)(Ab + NV + base);
            n2 = *(const uint2*)(Ab + 2 * NV + base);
        }
    }
    for (int j = 0; j < 34; ++j) {
        uint2 f0 = make_uint2(0u, 0u), f1 = f0, f2 = f0;
        int yy = y0 + j + 2 - R;
        if (j < 32 && (unsigned)yy < 128u) {
            int base = zs + yy * 128 + x0;
            f0 = *(const uint2*)(Ab + base);
            f1 = *(const uint2*)(Ab + NV + base);
            f2 = *(const uint2*)(Ab + 2 * NV + base);
        }
        float4 a0 = bf4_to_f4(c0), a1 = bf4_to_f4(c1), a2 = bf4_to_f4(c2);
#pragma unroll
        for (int t = 0; t < 4; ++t) {
            int i = j - t + 3;
            float w0 = kp[0][i], w1 = kp[1][i], w2 = kp[2][i];
            fma4(acc[0][t], w0, a0);
            fma4(acc[1][t], w1, a0);
            fma4(acc[2][t], w2, a0);
            fma4(acc[3][t], w0, a1);
            fma4(acc[4][t], w1, a1);
            fma4(acc[5][t], w0, a2);
        }
        c0 = n0; c1 = n1; c2 = n2;
        n0 = f0; n1 = f1; n2 = f2;
    }
#pragma unroll
    for (int t = 0; t < 4; ++t) {
        const int row = tz * 4 + t;
#pragma unroll
        for (int c = 0; c < 6; ++c) {
            uint2 pv = make_uint2(pack_bf2(acc[c][t].x, acc[c][t].y),
                                  pack_bf2(acc[c][t].z, acc[c][t].w));
            *reinterpret_cast<uint2*>(Bu2 + row * RSTRIDE + c * CSTRIDE + 16 + x0) = pv;
        }
    }

    {
        const int lane = threadIdx.x & 63;
        const unsigned long long below_mask = (1ull << lane) - 1ull;
#pragma unroll
        for (int k = 0; k < 4; ++k) {
            const unsigned w = pk[k];
#pragma unroll
            for (int t = 0; t < 4; ++t) {
                const int sv = (int)((w >> (8 * t)) & 255u);
                const int x = 4 * (q0_c + 8 * k) + t;
                const bool mt = (sv == label);
                const bool zt = !mt && (sv < 1 || sv > 8) &&
                                (((x & 7) + 1) == label);
                const bool pred = mt | zt;
                unsigned long long bal = __ballot(pred);
                int base = 0;
                if (lane == 0 && bal) base = atomicAdd(&cnt, (int)__popcll(bal));
                base = __shfl(base, 0);
                if (pred) {
                    int pos = base + (int)__popcll(bal & below_mask);
                    if (pos < LCAP)
                        lst[pos] = (unsigned short)((rr_c << 7) | x | (zt ? 0x8000 : 0));
                }
            }
        }
    }

    __syncthreads();

    const int total = cnt;
    if (total <= LCAP) {
        for (int e = threadIdx.x; e < total; e += 128) {
            int ent = lst[e];
            int rr = (ent >> 7) & 15, x = ent & 127;
            if (ent & 0x8000) zero_voxel(rr, x, z0, y0, out);
            else do_voxel_out(Bu2, rr, x, z0, y0, out, kw);
        }
    } else {
        for (int e = threadIdx.x; e < 2048; e += 128) {
            int rr = e >> 7, x = e & 127;
            int z2 = z0 + (rr >> 2), y2 = y0 + (rr & 3);
            int sv = (int)seg[(z2 * 128 + y2) * 128 + x] & 255;
            if (sv == label)
                do_voxel_out(Bu2, rr, x, z0, y0, out, kw);
            else if ((sv < 1 || sv > 8) && (((x & 7) + 1) == label))
                zero_voxel(rr, x, z0, y0, out);
        }
    }
}

__global__ __launch_bounds__(256) void seg_to_u8(const int* __restrict__ seg,
                                                 unsigned char* __restrict__ seg8) {
    const int t = blockIdx.x * 256 + threadIdx.x;          // 2048 blocks
    const int4 s = ((const int4*)seg)[t];
    ((uchar4*)seg8)[t] = make_uchar4((unsigned char)s.x, (unsigned char)s.y,
                                     (unsigned char)s.z, (unsigned char)s.w);
}

extern "C" void kernel_launch(void* const* d_in, const int* in_sizes, int n_in,
                              void* d_out, int out_size, void* d_ws, size_t ws_size,
                              hipStream_t stream) {
    const int* seg = (const int*)d_in[0];
    // d_in[1] (coords) unused: math is translation-invariant.
    float* out = (float*)d_out;
    unsigned short* A = (unsigned short*)d_ws;             // bf16 A planes
    const size_t AVOL = (size_t)3 * NV;                    // u16 elements/label

    Kw kw;
    double gg[KL], S = 0.0;
    for (int j = 0; j < KL; ++j) { double d = j - R; gg[j] = exp(-0.5 * d * d / 25.0); S += gg[j]; }
    for (int j = 0; j < KL; ++j) {
        double gn = gg[j] / S, d = j - R;
        kw.k0[j] = (float)gn;
        kw.k1[j] = (float)(-d * gn);   // conv kernel k1 evaluated at (Z - t) = -d
        kw.k2[j] = (float)(d * d * gn);
    }

    // No memset: every output voxel is written exactly once.

    const size_t need_all = 8 * AVOL * sizeof(unsigned short) + NV;  // A_all + seg8
    const size_t need_one = AVOL * sizeof(unsigned short) + NV;

    if (ws_size >= need_all) {
        // 3-dispatch path: all labels resident; pass_yx_all loops labels.
        unsigned char* seg8 = (unsigned char*)d_ws + 8 * AVOL * sizeof(unsigned short);
        seg_to_u8<<<dim3(2048), dim3(256), 0, stream>>>(seg, seg8);
        pass_z_t<unsigned char><<<dim3(512, 8), dim3(256), 0, stream>>>(
            seg8, A, 1, AVOL, kw);
        pass_yx_all<unsigned char><<<dim3(2048), dim3(256), 0, stream>>>(
            A, seg8, out, AVOL, kw);
    } else if (ws_size >= need_one) {
        unsigned char* seg8 = (unsigned char*)d_ws + AVOL * sizeof(unsigned short);
        seg_to_u8<<<dim3(2048), dim3(256), 0, stream>>>(seg, seg8);
        for (int label = 1; label <= 8; ++label) {
            pass_z_t<unsigned char><<<dim3(512, 1), dim3(256), 0, stream>>>(
                seg8, A, label, 0, kw);
            pass_yx<unsigned char><<<dim3(1024, 1), dim3(128), 0, stream>>>(
                A, seg8, out, label, 0, kw);
        }
    } else {
        for (int label = 1; label <= 8; ++label) {
            pass_z_t<int><<<dim3(512, 1), dim3(256), 0, stream>>>(
                seg, A, label, 0, kw);
            pass_yx<int><<<dim3(1024, 1), dim3(128), 0, stream>>>(
                A, seg, out, label, 0, kw);
        }
    }
}

// Round 6
// 488.023 us; speedup vs baseline: 1.3192x; 1.3192x over previous
//
#include <hip/hip_runtime.h>
#include <hip/hip_bf16.h>
#include <math.h>

// LSD (local shape descriptors), 128^3, 8 labels, sigma=5, truncate=3 -> 31-tap kernel.
//
// Algebra: for label mask m, define G_{abc} = (k_a *_z)(k_b *_y)(k_c *_x) m with
//   k0(u)=w(u), k1(u)=u w(u), k2(u)=u^2 w(u)  (w = normalized gaussian).
// At a voxel with mass=G000>0, p=G100/mass, q=G010/mass, s=G001/mass:
//   mean_offset = 0.5 - {p,q,s}/(2 sigma);  cov_ab = (G../mass - ..)/sigma^2.
// Translation-invariant: coords input not needed. Masks disjoint.
//
// R8: SPARSE phase 2 (LDS list, bf16 B rows): 487 us.
// R9: label-adjacent order, no-memset, pipelines: 422 (L2 thrash on A).
// R10: bf16 A + tile-major: 412. FETCH 61 MB. NOT BW-bound: latency/issue.
// R11: 2-deep pipes + ballot compaction: 407 (pass_yx 289, VALU 46%, occ 21%).
// R12: one block owns tile across 8 labels, f16 LDS out-stage: 452 (pass_yx
//      333). Occ 21->44%, WRITE 468->82 -- skeleton works; staging tax lost.
// R13: direct stores + x-consecutive spans + 18.4 KB LDS, BUT
//      __launch_bounds__(256,8) forced VGPR=32 -> massive scratch spills:
//      FETCH 300 MB / WRITE 796 MB of spill traffic, VALU 39%, 644 us total.
//      Lesson: never demand occupancy via launch_bounds beyond what the
//      register budget affords; occupancy is computed at runtime anyway.
// R14 (this round): single change -- launch_bounds (256,8) -> (256,4).
//      VGPR should return to ~52-64 (R12 measured 52 with a heavier
//      epilogue); LDS 18.4 KB allows 8 blk/CU; at <=64 VGPR the HW can
//      still schedule 8 waves/SIMD. Spills gone, structure of R13 finally
//      measurable.

constexpr int NV = 128 * 128 * 128;
constexpr int SLICE = 128 * 128;
constexpr int R = 15;
constexpr int KL = 31;
constexpr int CSTRIDE = 160;            // u16: 16 pad + 128 data + 16 pad
constexpr int RSTRIDE = 6 * CSTRIDE + 8; // 968 u16; row stagger
constexpr int LCAP = 512;

struct Kw { float k0[KL]; float k1[KL]; float k2[KL]; };

__device__ __forceinline__ void fma4(float4& a, float w, const float4& b) {
    a.x = fmaf(w, b.x, a.x); a.y = fmaf(w, b.y, a.y);
    a.z = fmaf(w, b.z, a.z); a.w = fmaf(w, b.w, a.w);
}

__device__ __forceinline__ float4 load_mask4(const unsigned char* p, int lab) {
    unsigned int u = *(const unsigned int*)p;
    return make_float4(((u       ) & 255u) == (unsigned)lab ? 1.f : 0.f,
                       ((u >>  8 ) & 255u) == (unsigned)lab ? 1.f : 0.f,
                       ((u >> 16 ) & 255u) == (unsigned)lab ? 1.f : 0.f,
                       ((u >> 24 ) & 255u) == (unsigned)lab ? 1.f : 0.f);
}
__device__ __forceinline__ float4 load_mask4(const int* p, int lab) {
    int4 s = *(const int4*)p;
    return make_float4(s.x == lab ? 1.f : 0.f, s.y == lab ? 1.f : 0.f,
                       s.z == lab ? 1.f : 0.f, s.w == lab ? 1.f : 0.f);
}

__device__ __forceinline__ unsigned seg_pack4(const unsigned char* p) {
    return *(const unsigned int*)p;
}
__device__ __forceinline__ unsigned seg_pack4(const int* p) {
    int4 v = *(const int4*)p;
    return (unsigned)(v.x & 255) | ((unsigned)(v.y & 255) << 8) |
           ((unsigned)(v.z & 255) << 16) | ((unsigned)(v.w & 255) << 24);
}

__device__ __forceinline__ float bf_ld(const unsigned short* p) {
    return __uint_as_float(((unsigned int)(*p)) << 16);
}

// 4 packed bf16 (as uint2) -> float4. 1 VALU op per value.
__device__ __forceinline__ float4 bf4_to_f4(uint2 u) {
    return make_float4(__uint_as_float(u.x << 16),
                       __uint_as_float(u.x & 0xFFFF0000u),
                       __uint_as_float(u.y << 16),
                       __uint_as_float(u.y & 0xFFFF0000u));
}

__device__ __forceinline__ unsigned pack_bf2(float a, float b) {
    __hip_bfloat162 h = __float22bfloat162_rn(make_float2(a, b));
    return *reinterpret_cast<unsigned*>(&h);
}

// -------- pass_z: seg -> A[lab][3] bf16 (z-conv). grid (512, nlab), 256 thr.
template <typename ST>
__global__ __launch_bounds__(256) void pass_z_t(const ST* __restrict__ seg,
                                                unsigned short* __restrict__ A,
                                                int label0, size_t a_stride,
                                                Kw kw) {
    __shared__ float kp[3][37];           // zero-padded: kp[c][i] = k_c[i-3]
    if (threadIdx.x < 37) {
        int i = threadIdx.x, j = i - 3; bool ok = (j >= 0) && (j < KL);
        kp[0][i] = ok ? kw.k0[j] : 0.f;
        kp[1][i] = ok ? kw.k1[j] : 0.f;
        kp[2][i] = ok ? kw.k2[j] : 0.f;
    }
    __syncthreads();
    const int label = label0 + blockIdx.y;
    unsigned short* Ab = A + (size_t)blockIdx.y * a_stride;
    const int h = blockIdx.x, g = h & 7, l = h >> 3;       // 512 x-blocks
    const int tx = threadIdx.x & 31, ty = threadIdx.x >> 5;
    const int x0 = tx * 4;
    const int z0 = 16 * g + 4 * (l & 3);                   // XCD g owns z [16g,16g+16)
    const int y  = (l >> 2) * 8 + ty;

    float4 acc[4][3];
#pragma unroll
    for (int t = 0; t < 4; ++t)
#pragma unroll
        for (int c = 0; c < 3; ++c) acc[t][c] = make_float4(0.f, 0.f, 0.f, 0.f);

    // 2-deep pipelined sliding window: load j+2 while FMAing j.
    float4 cm = make_float4(0.f, 0.f, 0.f, 0.f), nm = cm;
    {
        int zz = z0 - R;
        if ((unsigned)zz < 128u)
            cm = load_mask4(seg + (zz * SLICE + y * 128 + x0), label);
        int zn = z0 + 1 - R;
        if ((unsigned)zn < 128u)
            nm = load_mask4(seg + (zn * SLICE + y * 128 + x0), label);
    }
    for (int j = 0; j < 34; ++j) {                         // window: 4 outs + 30
        float4 fm = make_float4(0.f, 0.f, 0.f, 0.f);
        int zz = z0 + j + 2 - R;                           // uniform per wave
        if (j < 32 && (unsigned)zz < 128u)
            fm = load_mask4(seg + (zz * SLICE + y * 128 + x0), label);
#pragma unroll
        for (int t = 0; t < 4; ++t) {
            int i = j - t + 3;                             // padded weight index
            fma4(acc[t][0], kp[0][i], cm);
            fma4(acc[t][1], kp[1][i], cm);
            fma4(acc[t][2], kp[2][i], cm);
        }
        cm = nm; nm = fm;
    }
#pragma unroll
    for (int t = 0; t < 4; ++t) {
        int base = (z0 + t) * SLICE + y * 128 + x0;
#pragma unroll
        for (int c = 0; c < 3; ++c) {
            float4 v = acc[t][c];
            uint2 pv = make_uint2(pack_bf2(v.x, v.y), pack_bf2(v.z, v.w));
            *reinterpret_cast<uint2*>(Ab + (size_t)c * NV + base) = pv;
        }
    }
}

// ---- per-voxel sparse x-conv (B rows in bf16 LDS, zero-padded) ----
__device__ __forceinline__ void conv_voxel(const unsigned short* __restrict__ Bu,
                                           int rr, int x, const Kw& kw,
                                           float o[10]) {
    const unsigned short* row = Bu + rr * RSTRIDE + (x + 1);
    float g000 = 0, g001 = 0, g002 = 0, g010 = 0, g011 = 0,
          g020 = 0, g100 = 0, g101 = 0, g110 = 0, g200 = 0;
#pragma unroll
    for (int j = 0; j < KL; ++j) {
        float w0 = kw.k0[j], w1 = kw.k1[j], w2 = kw.k2[j];
        float b0 = bf_ld(row + 0 * CSTRIDE + j);
        float b1 = bf_ld(row + 1 * CSTRIDE + j);
        float b2 = bf_ld(row + 2 * CSTRIDE + j);
        float b3 = bf_ld(row + 3 * CSTRIDE + j);
        float b4 = bf_ld(row + 4 * CSTRIDE + j);
        float b5 = bf_ld(row + 5 * CSTRIDE + j);
        g000 = fmaf(w0, b0, g000); g001 = fmaf(w1, b0, g001); g002 = fmaf(w2, b0, g002);
        g010 = fmaf(w0, b1, g010); g011 = fmaf(w1, b1, g011);
        g020 = fmaf(w0, b2, g020);
        g100 = fmaf(w0, b3, g100); g101 = fmaf(w1, b3, g101);
        g110 = fmaf(w0, b4, g110);
        g200 = fmaf(w0, b5, g200);
    }
    float mass = g000;
    float denom = (mass > 0.f) ? mass : 1.f;
    float inv = 1.f / denom;
    float p = g100 * inv, q = g010 * inv, s = g001 * inv;
    const float cs = 1.0f / 25.0f;                         // 1/sigma^2
    o[0] = 0.5f - 0.1f * p;                                // 1/(2 sigma) = 0.1
    o[1] = 0.5f - 0.1f * q;
    o[2] = 0.5f - 0.1f * s;
    o[3] = (g200 * inv - p * p) * cs;
    o[4] = (g020 * inv - q * q) * cs;
    o[5] = (g002 * inv - s * s) * cs;
    o[6] = (g110 * inv - p * q) * cs;
    o[7] = (g011 * inv - q * s) * cs;
    o[8] = (g101 * inv - p * s) * cs;
    o[9] = mass;
#pragma unroll
    for (int c = 0; c < 10; ++c) o[c] = fminf(fmaxf(o[c], 0.f), 1.f);
}

__device__ __forceinline__ void do_voxel_out(const unsigned short* __restrict__ Bu,
                                             int rr, int x, int z0, int y0,
                                             float* __restrict__ out, const Kw& kw) {
    float o[10];
    conv_voxel(Bu, rr, x, kw, o);
    const int z2 = z0 + (rr >> 2), y2 = y0 + (rr & 3);
    const int v = (z2 * 128 + y2) * 128 + x;
#pragma unroll
    for (int c = 0; c < 10; ++c) out[(size_t)c * NV + v] = o[c];
}

__device__ __forceinline__ void zero_voxel(int rr, int x, int z0, int y0,
                                           float* __restrict__ out) {
    const int z2 = z0 + (rr >> 2), y2 = y0 + (rr & 3);
    const int v = (z2 * 128 + y2) * 128 + x;
#pragma unroll
    for (int c = 0; c < 10; ++c) out[(size_t)c * NV + v] = 0.f;
}

// -------- pass_yx_all: A[8][3] bf16 -> out. grid (2048), 256 thr. ----------
// One block = one 8-row tile (2z x 4y x 128x), loops over all 8 labels.
// Per label: phase 1 (4 waves = 2 z-rows x 2 channel-groups) -> Bu bf16;
// ballot compaction over contiguous wave-owned 64-voxel spans (x-consecutive
// list); sparse phase 2 writes f32 descriptors (and zeros) direct to out.
// launch_bounds (256,4): R13's (256,8) forced VGPR=32 -> scratch spills.
template <typename ST>
__global__ __launch_bounds__(256, 4) void pass_yx_all(
        const unsigned short* __restrict__ A,
        const ST* __restrict__ seg,
        float* __restrict__ out,
        size_t a_stride, Kw kw) {
    __shared__ float4 kq4[40];                              // {k0,k1,k2,0}[i-3]
    __shared__ __align__(16) unsigned short Bu[8 * RSTRIDE];   // 15,488 B
    __shared__ unsigned seg_l[256];                            // tile seg bytes, 1 KB
    __shared__ unsigned short lst[LCAP];                       // 1 KB
    __shared__ int cnt2[2];

    // init: zero Bu (pads must be 0), weights, counters, seg_lds
    {
        uint4 z4 = make_uint4(0, 0, 0, 0);
        uint4* b4 = (uint4*)Bu;                            // 8*968/8 = 968
        for (int i = threadIdx.x; i < 968; i += 256) b4[i] = z4;
    }
    if (threadIdx.x < 40) {
        int i = threadIdx.x, j = i - 3; bool ok = (j >= 0) && (j < KL);
        kq4[i] = make_float4(ok ? kw.k0[j] : 0.f, ok ? kw.k1[j] : 0.f,
                             ok ? kw.k2[j] : 0.f, 0.f);
    }
    if (threadIdx.x == 0) { cnt2[0] = 0; cnt2[1] = 0; }

    const int b = blockIdx.x, g = b & 7, l = b >> 3;       // 2048 tiles
    const int z0 = 16 * g + 2 * (l & 7);                   // XCD g owns z slab
    const int y0 = (l >> 3) * 4;                           // 32 y-tiles

    // seg for this tile, once: thread t owns voxels 4t..4t+3 (v = rr*128+x)
    const unsigned pk = seg_pack4(seg +
        ((z0 + (threadIdx.x >> 7)) * 128 + (y0 + ((threadIdx.x >> 5) & 3))) * 128 +
        (threadIdx.x & 31) * 4);
    seg_l[threadIdx.x] = pk;

    // phase-1 wave roles
    const int w = threadIdx.x >> 6;
    const int zr = w & 1, cg = w >> 1;                     // z-row, channel group
    const int lane = threadIdx.x & 63;
    const int lx = lane & 31, lh = lane >> 5;
    const int x0 = 4 * lx;                                 // u16 elements
    const int t0 = 2 * lh;                                 // this half-wave's y-outs
    const int zrs = (z0 + zr) * SLICE;
    const unsigned long long below_mask = (1ull << lane) - 1ull;

    __syncthreads();

    for (int labi = 0; labi < 8; ++labi) {
        const int label = 1 + labi;
        const unsigned short* Ab0 = A + (size_t)labi * a_stride;
        const unsigned short* Ab1 = Ab0 + NV;
        const unsigned short* Ab2 = Ab0 + 2 * NV;

        // ---- phase 1: y-conv into registers (overlaps prev label's phase 2
        //      on other waves; touches no mutable shared state) ----
        float4 acc[3][2];
#pragma unroll
        for (int c = 0; c < 3; ++c)
#pragma unroll
            for (int k = 0; k < 2; ++k) acc[c][k] = make_float4(0.f, 0.f, 0.f, 0.f);

        uint2 u0c = make_uint2(0u, 0u), u0n = u0c;
        uint2 u1c = u0c, u1n = u0c, u2c = u0c, u2n = u0c;
        {
            int yy = y0 - R;
            if ((unsigned)yy < 128u) {
                int base = zrs + yy * 128 + x0;
                if (cg == 0) u0c = *(const uint2*)(Ab0 + base);
                else { u1c = *(const uint2*)(Ab1 + base); u2c = *(const uint2*)(Ab2 + base); }
            }
            int yn = y0 + 1 - R;
            if ((unsigned)yn < 128u) {
                int base = zrs + yn * 128 + x0;
                if (cg == 0) u0n = *(const uint2*)(Ab0 + base);
                else { u1n = *(const uint2*)(Ab1 + base); u2n = *(const uint2*)(Ab2 + base); }
            }
        }
        for (int j = 0; j < 34; ++j) {
            uint2 f0 = make_uint2(0u, 0u), f1 = f0, f2 = f0;
            int yy = y0 + j + 2 - R;
            if (j < 32 && (unsigned)yy < 128u) {
                int base = zrs + yy * 128 + x0;
                if (cg == 0) f0 = *(const uint2*)(Ab0 + base);
                else { f1 = *(const uint2*)(Ab1 + base); f2 = *(const uint2*)(Ab2 + base); }
            }
            if (cg == 0) {
                float4 a0 = bf4_to_f4(u0c);
#pragma unroll
                for (int k = 0; k < 2; ++k) {
                    float4 wv = kq4[j + 3 - (t0 + k)];
                    fma4(acc[0][k], wv.x, a0);
                    fma4(acc[1][k], wv.y, a0);
                    fma4(acc[2][k], wv.z, a0);
                }
            } else {
                float4 a1 = bf4_to_f4(u1c), a2 = bf4_to_f4(u2c);
#pragma unroll
                for (int k = 0; k < 2; ++k) {
                    float4 wv = kq4[j + 3 - (t0 + k)];
                    fma4(acc[0][k], wv.x, a1);
                    fma4(acc[1][k], wv.y, a1);
                    fma4(acc[2][k], wv.x, a2);
                }
            }
            u0c = u0n; u1c = u1n; u2c = u2n;
            u0n = f0;  u1n = f1;  u2n = f2;
        }

        __syncthreads();   // prev label's phase 2 done reading Bu/lst/cnt

        // ---- epilogue: write Bu; compact this label's voxels ----
#pragma unroll
        for (int k = 0; k < 2; ++k) {
            const int row = zr * 4 + t0 + k;
#pragma unroll
            for (int c3 = 0; c3 < 3; ++c3) {
                const int c = cg * 3 + c3;
                float4 v = acc[c3][k];
                uint2 pv = make_uint2(pack_bf2(v.x, v.y), pack_bf2(v.z, v.w));
                *reinterpret_cast<uint2*>(Bu + row * RSTRIDE + c * CSTRIDE + 16 + x0) = pv;
            }
        }
        {
            int* cw = &cnt2[labi & 1];
            const unsigned char* s8 = (const unsigned char*)seg_l;
#pragma unroll
            for (int s = 0; s < 4; ++s) {
                const int v = (w << 8) + (s << 6) + lane;  // contiguous span
                const int sv = (int)s8[v];
                const bool mt = (sv == label);
                const bool zt = !mt && (sv < 1 || sv > 8) &&
                                (((v & 7) + 1) == label);
                const bool pred = mt | zt;
                unsigned long long bal = __ballot(pred);
                int base = 0;
                if (lane == 0 && bal) base = atomicAdd(cw, (int)__popcll(bal));
                base = __shfl(base, 0);
                if (pred) {
                    int pos = base + (int)__popcll(bal & below_mask);
                    if (pos < LCAP)
                        lst[pos] = (unsigned short)(v | (zt ? 0x8000 : 0));
                }
            }
            if (threadIdx.x == 0) cnt2[(labi + 1) & 1] = 0;
        }

        __syncthreads();   // Bu + lst + cnt visible

        // ---- phase 2: sparse x-conv + direct f32 stores ----
        const int total = cnt2[labi & 1];
        if (total <= LCAP) {
            for (int e = threadIdx.x; e < total; e += 256) {
                int ent = lst[e];
                int v = ent & 1023, rr = v >> 7, x = v & 127;
                const int gb = ((z0 + (rr >> 2)) * 128 + (y0 + (rr & 3))) * 128 + x;
                if (ent & 0x8000) {
#pragma unroll
                    for (int c = 0; c < 10; ++c) out[(size_t)c * NV + gb] = 0.f;
                } else {
                    float o[10];
                    conv_voxel(Bu, rr, x, kw, o);
#pragma unroll
                    for (int c = 0; c < 10; ++c) out[(size_t)c * NV + gb] = o[c];
                }
            }
        } else {
            // adversarial-density fallback: each thread sweeps its 4 voxels
#pragma unroll
            for (int t = 0; t < 4; ++t) {
                const int sv = (int)((pk >> (8 * t)) & 255u);
                const int v = 4 * (int)threadIdx.x + t;
                const int rr = v >> 7, x = v & 127;
                const int gb = ((z0 + (rr >> 2)) * 128 + (y0 + (rr & 3))) * 128 + x;
                if (sv == label) {
                    float o[10];
                    conv_voxel(Bu, rr, x, kw, o);
#pragma unroll
                    for (int c = 0; c < 10; ++c) out[(size_t)c * NV + gb] = o[c];
                } else if ((sv < 1 || sv > 8) && (((v & 7) + 1) == label)) {
#pragma unroll
                    for (int c = 0; c < 10; ++c) out[(size_t)c * NV + gb] = 0.f;
                }
            }
        }
    }
}

// -------- fallback pass_yx (per-label, scatter writes) — R11 version ------
template <typename ST>
__global__ __launch_bounds__(128) void pass_yx(const unsigned short* __restrict__ A,
                                               const ST* __restrict__ seg,
                                               float* __restrict__ out,
                                               int label0, size_t a_stride,
                                               Kw kw) {
    __shared__ float kp[3][37];
    __shared__ __align__(16) unsigned short Bu2[16 * RSTRIDE];
    __shared__ unsigned short lst[LCAP];
    __shared__ int cnt;

    {
        uint4 z4 = make_uint4(0, 0, 0, 0);
        uint4* b4 = (uint4*)Bu2;
        for (int i = threadIdx.x; i < 1936; i += 128) b4[i] = z4;
    }
    if (threadIdx.x < 37) {
        int i = threadIdx.x, j = i - 3; bool ok = (j >= 0) && (j < KL);
        kp[0][i] = ok ? kw.k0[j] : 0.f;
        kp[1][i] = ok ? kw.k1[j] : 0.f;
        kp[2][i] = ok ? kw.k2[j] : 0.f;
    }
    if (threadIdx.x == 0) cnt = 0;
    __syncthreads();

    const int labi = blockIdx.y;
    const int label = label0 + labi;
    const unsigned short* Ab = A + (size_t)labi * a_stride;
    const int h = blockIdx.x, g = h & 7, l = h >> 3;
    const int tx = threadIdx.x & 31, tz = threadIdx.x >> 5;
    const int x0 = tx * 4;
    const int z0 = 16 * g + 4 * (l & 3);
    const int y0 = (l >> 2) * 4;
    const int zs = (z0 + tz) * SLICE;

    const int rr_c = threadIdx.x >> 3, q0_c = threadIdx.x & 7;
    const int vrow_c = ((z0 + (rr_c >> 2)) * 128 + (y0 + (rr_c & 3))) * 128;
    unsigned pk[4];
#pragma unroll
    for (int k = 0; k < 4; ++k)
        pk[k] = seg_pack4(seg + vrow_c + 4 * (q0_c + 8 * k));

    float4 acc[6][4];
#pragma unroll
    for (int c = 0; c < 6; ++c)
#pragma unroll
        for (int t = 0; t < 4; ++t) acc[c][t] = make_float4(0.f, 0.f, 0.f, 0.f);

    uint2 c0 = make_uint2(0u, 0u), c1 = c0, c2 = c0;
    uint2 n0 = c0, n1 = c0, n2 = c0;
    {
        int yy = y0 - R;
        if ((unsigned)yy < 128u) {
            int base = zs + yy * 128 + x0;
            c0 = *(const uint2*)(Ab + base);
            c1 = *(const uint2*)(Ab + NV + base);
            c2 = *(const uint2*)(Ab + 2 * NV + base);
        }
        int yn = y0 + 1 - R;
        if ((unsigned)yn < 128u) {
            int base = zs + yn * 128 + x0;
            n0 = *(const uint2*)(Ab + base);
            n1 = *(const uint2*)(Ab + NV + base);
            n2 = *(const uint2*)(Ab + 2 * NV + base);
        }
    }
    for (int j = 0; j < 34; ++j) {
        uint2 f0 = make_uint2(0u, 0u), f1 = f0, f2 = f0;
        int yy = y0 + j + 2 - R;
        if (j < 32 && (unsigned)yy < 128u) {
            int base = zs + yy * 128 + x0;
            f0 = *(const uint2*)(Ab + base);
            f1 = *(const uint2*)(Ab + NV + base);
            f2 = *(const uint2*)(Ab + 2 * NV + base);
        }
        float4 a0 = bf4_to_f4(c0), a1 = bf4_to_f4(c1), a2 = bf4_to_f4(c2);
#pragma unroll
        for (int t = 0; t < 4; ++t) {
            int i = j - t + 3;
            float w0 = kp[0][i], w1 = kp[1][i], w2 = kp[2][i];
            fma4(acc[0][t], w0, a0);
            fma4(acc[1][t], w1, a0);
            fma4(acc[2][t], w2, a0);
            fma4(acc[3][t], w0, a1);
            fma4(acc[4][t], w1, a1);
            fma4(acc[5][t], w0, a2);
        }
        c0 = n0; c1 = n1; c2 = n2;
        n0 = f0; n1 = f1; n2 = f2;
    }
#pragma unroll
    for (int t = 0; t < 4; ++t) {
        const int row = tz * 4 + t;
#pragma unroll
        for (int c = 0; c < 6; ++c) {
            uint2 pv = make_uint2(pack_bf2(acc[c][t].x, acc[c][t].y),
                                  pack_bf2(acc[c][t].z, acc[c][t].w));
            *reinterpret_cast<uint2*>(Bu2 + row * RSTRIDE + c * CSTRIDE + 16 + x0) = pv;
        }
    }

    {
        const int lane = threadIdx.x & 63;
        const unsigned long long below_mask = (1ull << lane) - 1ull;
#pragma unroll
        for (int k = 0; k < 4; ++k) {
            const unsigned w = pk[k];
#pragma unroll
            for (int t = 0; t < 4; ++t) {
                const int sv = (int)((w >> (8 * t)) & 255u);
                const int x = 4 * (q0_c + 8 * k) + t;
                const bool mt = (sv == label);
                const bool zt = !mt && (sv < 1 || sv > 8) &&
                                (((x & 7) + 1) == label);
                const bool pred = mt | zt;
                unsigned long long bal = __ballot(pred);
                int base = 0;
                if (lane == 0 && bal) base = atomicAdd(&cnt, (int)__popcll(bal));
                base = __shfl(base, 0);
                if (pred) {
                    int pos = base + (int)__popcll(bal & below_mask);
                    if (pos < LCAP)
                        lst[pos] = (unsigned short)((rr_c << 7) | x | (zt ? 0x8000 : 0));
                }
            }
        }
    }

    __syncthreads();

    const int total = cnt;
    if (total <= LCAP) {
        for (int e = threadIdx.x; e < total; e += 128) {
            int ent = lst[e];
            int rr = (ent >> 7) & 15, x = ent & 127;
            if (ent & 0x8000) zero_voxel(rr, x, z0, y0, out);
            else do_voxel_out(Bu2, rr, x, z0, y0, out, kw);
        }
    } else {
        for (int e = threadIdx.x; e < 2048; e += 128) {
            int rr = e >> 7, x = e & 127;
            int z2 = z0 + (rr >> 2), y2 = y0 + (rr & 3);
            int sv = (int)seg[(z2 * 128 + y2) * 128 + x] & 255;
            if (sv == label)
                do_voxel_out(Bu2, rr, x, z0, y0, out, kw);
            else if ((sv < 1 || sv > 8) && (((x & 7) + 1) == label))
                zero_voxel(rr, x, z0, y0, out);
        }
    }
}

__global__ __launch_bounds__(256) void seg_to_u8(const int* __restrict__ seg,
                                                 unsigned char* __restrict__ seg8) {
    const int t = blockIdx.x * 256 + threadIdx.x;          // 2048 blocks
    const int4 s = ((const int4*)seg)[t];
    ((uchar4*)seg8)[t] = make_uchar4((unsigned char)s.x, (unsigned char)s.y,
                                     (unsigned char)s.z, (unsigned char)s.w);
}

extern "C" void kernel_launch(void* const* d_in, const int* in_sizes, int n_in,
                              void* d_out, int out_size, void* d_ws, size_t ws_size,
                              hipStream_t stream) {
    const int* seg = (const int*)d_in[0];
    // d_in[1] (coords) unused: math is translation-invariant.
    float* out = (float*)d_out;
    unsigned short* A = (unsigned short*)d_ws;             // bf16 A planes
    const size_t AVOL = (size_t)3 * NV;                    // u16 elements/label

    Kw kw;
    double gg[KL], S = 0.0;
    for (int j = 0; j < KL; ++j) { double d = j - R; gg[j] = exp(-0.5 * d * d / 25.0); S += gg[j]; }
    for (int j = 0; j < KL; ++j) {
        double gn = gg[j] / S, d = j - R;
        kw.k0[j] = (float)gn;
        kw.k1[j] = (float)(-d * gn);   // conv kernel k1 evaluated at (Z - t) = -d
        kw.k2[j] = (float)(d * d * gn);
    }

    // No memset: every output voxel is written exactly once.

    const size_t need_all = 8 * AVOL * sizeof(unsigned short) + NV;  // A_all + seg8
    const size_t need_one = AVOL * sizeof(unsigned short) + NV;

    if (ws_size >= need_all) {
        // 3-dispatch path: all labels resident; pass_yx_all loops labels.
        unsigned char* seg8 = (unsigned char*)d_ws + 8 * AVOL * sizeof(unsigned short);
        seg_to_u8<<<dim3(2048), dim3(256), 0, stream>>>(seg, seg8);
        pass_z_t<unsigned char><<<dim3(512, 8), dim3(256), 0, stream>>>(
            seg8, A, 1, AVOL, kw);
        pass_yx_all<unsigned char><<<dim3(2048), dim3(256), 0, stream>>>(
            A, seg8, out, AVOL, kw);
    } else if (ws_size >= need_one) {
        unsigned char* seg8 = (unsigned char*)d_ws + AVOL * sizeof(unsigned short);
        seg_to_u8<<<dim3(2048), dim3(256), 0, stream>>>(seg, seg8);
        for (int label = 1; label <= 8; ++label) {
            pass_z_t<unsigned char><<<dim3(512, 1), dim3(256), 0, stream>>>(
                seg8, A, label, 0, kw);
            pass_yx<unsigned char><<<dim3(1024, 1), dim3(128), 0, stream>>>(
                A, seg8, out, label, 0, kw);
        }
    } else {
        for (int label = 1; label <= 8; ++label) {
            pass_z_t<int><<<dim3(512, 1), dim3(256), 0, stream>>>(
                seg, A, label, 0, kw);
            pass_yx<int><<<dim3(1024, 1), dim3(128), 0, stream>>>(
                A, seg, out, label, 0, kw);
        }
    }
}

// Round 7
// 432.657 us; speedup vs baseline: 1.4880x; 1.1280x over previous
//
#include <hip/hip_runtime.h>
#include <hip/hip_bf16.h>
#include <math.h>

// LSD (local shape descriptors), 128^3, 8 labels, sigma=5, truncate=3 -> 31-tap kernel.
//
// Algebra: for label mask m, define G_{abc} = (k_a *_z)(k_b *_y)(k_c *_x) m with
//   k0(u)=w(u), k1(u)=u w(u), k2(u)=u^2 w(u)  (w = normalized gaussian).
// At a voxel with mass=G000>0, p=G100/mass, q=G010/mass, s=G001/mass:
//   mean_offset = 0.5 - {p,q,s}/(2 sigma);  cov_ab = (G../mass - ..)/sigma^2.
// Translation-invariant: coords input not needed. Masks disjoint.
//
// R8: SPARSE phase 2 (LDS list, bf16 B rows): 487 us.
// R10: bf16 A + tile-major: 412. FETCH 61 MB. NOT BW-bound: latency/issue.
// R11: 2-deep pipes + ballot compaction: 407 (pass_yx 289, VALU 46%, occ 21%,
//      10 waves/CU LDS-capped).
// R12: block-owns-8-labels + f16 stage: 452. Occ 44% but stage tax.
// R13: (256,8) launch bound -> VGPR 32 -> spills: 644.
// R14: bound (256,4): 488 (yx_all 380). CONCLUSION: R12+ wave-role split is
//      structurally bad -- half-waves duplicated every A load (t0 doesn't
//      affect addresses) and each load fed only 3-6 fma4 vs R11's 12; plus a
//      16-barrier serial chain per block. Occupancy could not buy that back.
// R15 (this round): R11 thread geometry + R12 occupancy, no mistakes.
//   - grid (2048, 8), 128 thr. Tile = 8 rows (2z x 4y x 128x).
//   - wave 0 = plane A0 (B0..B2), wave 1 = planes A1,A2 (B3..B5); bit5 = z-row.
//     NO duplicated loads; T=4 y-outs kept (R5/R6 cliff avoided); 12 fma4
//     per load on wave 0.
//   - LDS 18.2 KB -> 8 blk/CU = 16 waves/CU cap (2x R11).
//   - keep: span-contiguous ballot compaction (x-consecutive list), direct
//     f32 stores, zero-designation no-memset, 2-deep pipelines, plain
//     __launch_bounds__(128) (R13 lesson: never force waves via bounds).

constexpr int NV = 128 * 128 * 128;
constexpr int SLICE = 128 * 128;
constexpr int R = 15;
constexpr int KL = 31;
constexpr int CSTRIDE = 160;            // u16: 16 pad + 128 data + 16 pad
constexpr int RSTRIDE = 6 * CSTRIDE + 8; // 968 u16; row stagger
constexpr int LCAP = 512;

struct Kw { float k0[KL]; float k1[KL]; float k2[KL]; };

__device__ __forceinline__ void fma4(float4& a, float w, const float4& b) {
    a.x = fmaf(w, b.x, a.x); a.y = fmaf(w, b.y, a.y);
    a.z = fmaf(w, b.z, a.z); a.w = fmaf(w, b.w, a.w);
}

__device__ __forceinline__ float4 load_mask4(const unsigned char* p, int lab) {
    unsigned int u = *(const unsigned int*)p;
    return make_float4(((u       ) & 255u) == (unsigned)lab ? 1.f : 0.f,
                       ((u >>  8 ) & 255u) == (unsigned)lab ? 1.f : 0.f,
                       ((u >> 16 ) & 255u) == (unsigned)lab ? 1.f : 0.f,
                       ((u >> 24 ) & 255u) == (unsigned)lab ? 1.f : 0.f);
}
__device__ __forceinline__ float4 load_mask4(const int* p, int lab) {
    int4 s = *(const int4*)p;
    return make_float4(s.x == lab ? 1.f : 0.f, s.y == lab ? 1.f : 0.f,
                       s.z == lab ? 1.f : 0.f, s.w == lab ? 1.f : 0.f);
}

__device__ __forceinline__ unsigned seg_pack4(const unsigned char* p) {
    return *(const unsigned int*)p;
}
__device__ __forceinline__ unsigned seg_pack4(const int* p) {
    int4 v = *(const int4*)p;
    return (unsigned)(v.x & 255) | ((unsigned)(v.y & 255) << 8) |
           ((unsigned)(v.z & 255) << 16) | ((unsigned)(v.w & 255) << 24);
}

__device__ __forceinline__ float bf_ld(const unsigned short* p) {
    return __uint_as_float(((unsigned int)(*p)) << 16);
}

// 4 packed bf16 (as uint2) -> float4. 1 VALU op per value.
__device__ __forceinline__ float4 bf4_to_f4(uint2 u) {
    return make_float4(__uint_as_float(u.x << 16),
                       __uint_as_float(u.x & 0xFFFF0000u),
                       __uint_as_float(u.y << 16),
                       __uint_as_float(u.y & 0xFFFF0000u));
}

__device__ __forceinline__ unsigned pack_bf2(float a, float b) {
    __hip_bfloat162 h = __float22bfloat162_rn(make_float2(a, b));
    return *reinterpret_cast<unsigned*>(&h);
}

// -------- pass_z: seg -> A[lab][3] bf16 (z-conv). grid (512, nlab), 256 thr.
template <typename ST>
__global__ __launch_bounds__(256) void pass_z_t(const ST* __restrict__ seg,
                                                unsigned short* __restrict__ A,
                                                int label0, size_t a_stride,
                                                Kw kw) {
    __shared__ float kp[3][37];           // zero-padded: kp[c][i] = k_c[i-3]
    if (threadIdx.x < 37) {
        int i = threadIdx.x, j = i - 3; bool ok = (j >= 0) && (j < KL);
        kp[0][i] = ok ? kw.k0[j] : 0.f;
        kp[1][i] = ok ? kw.k1[j] : 0.f;
        kp[2][i] = ok ? kw.k2[j] : 0.f;
    }
    __syncthreads();
    const int label = label0 + blockIdx.y;
    unsigned short* Ab = A + (size_t)blockIdx.y * a_stride;
    const int h = blockIdx.x, g = h & 7, l = h >> 3;       // 512 x-blocks
    const int tx = threadIdx.x & 31, ty = threadIdx.x >> 5;
    const int x0 = tx * 4;
    const int z0 = 16 * g + 4 * (l & 3);                   // XCD g owns z [16g,16g+16)
    const int y  = (l >> 2) * 8 + ty;

    float4 acc[4][3];
#pragma unroll
    for (int t = 0; t < 4; ++t)
#pragma unroll
        for (int c = 0; c < 3; ++c) acc[t][c] = make_float4(0.f, 0.f, 0.f, 0.f);

    // 2-deep pipelined sliding window: load j+2 while FMAing j.
    float4 cm = make_float4(0.f, 0.f, 0.f, 0.f), nm = cm;
    {
        int zz = z0 - R;
        if ((unsigned)zz < 128u)
            cm = load_mask4(seg + (zz * SLICE + y * 128 + x0), label);
        int zn = z0 + 1 - R;
        if ((unsigned)zn < 128u)
            nm = load_mask4(seg + (zn * SLICE + y * 128 + x0), label);
    }
    for (int j = 0; j < 34; ++j) {                         // window: 4 outs + 30
        float4 fm = make_float4(0.f, 0.f, 0.f, 0.f);
        int zz = z0 + j + 2 - R;                           // uniform per wave
        if (j < 32 && (unsigned)zz < 128u)
            fm = load_mask4(seg + (zz * SLICE + y * 128 + x0), label);
#pragma unroll
        for (int t = 0; t < 4; ++t) {
            int i = j - t + 3;                             // padded weight index
            fma4(acc[t][0], kp[0][i], cm);
            fma4(acc[t][1], kp[1][i], cm);
            fma4(acc[t][2], kp[2][i], cm);
        }
        cm = nm; nm = fm;
    }
#pragma unroll
    for (int t = 0; t < 4; ++t) {
        int base = (z0 + t) * SLICE + y * 128 + x0;
#pragma unroll
        for (int c = 0; c < 3; ++c) {
            float4 v = acc[t][c];
            uint2 pv = make_uint2(pack_bf2(v.x, v.y), pack_bf2(v.z, v.w));
            *reinterpret_cast<uint2*>(Ab + (size_t)c * NV + base) = pv;
        }
    }
}

// ---- per-voxel sparse x-conv (B rows in bf16 LDS, zero-padded) ----
__device__ __forceinline__ void conv_voxel(const unsigned short* __restrict__ Bu,
                                           int rr, int x, const Kw& kw,
                                           float o[10]) {
    const unsigned short* row = Bu + rr * RSTRIDE + (x + 1);
    float g000 = 0, g001 = 0, g002 = 0, g010 = 0, g011 = 0,
          g020 = 0, g100 = 0, g101 = 0, g110 = 0, g200 = 0;
#pragma unroll
    for (int j = 0; j < KL; ++j) {
        float w0 = kw.k0[j], w1 = kw.k1[j], w2 = kw.k2[j];
        float b0 = bf_ld(row + 0 * CSTRIDE + j);
        float b1 = bf_ld(row + 1 * CSTRIDE + j);
        float b2 = bf_ld(row + 2 * CSTRIDE + j);
        float b3 = bf_ld(row + 3 * CSTRIDE + j);
        float b4 = bf_ld(row + 4 * CSTRIDE + j);
        float b5 = bf_ld(row + 5 * CSTRIDE + j);
        g000 = fmaf(w0, b0, g000); g001 = fmaf(w1, b0, g001); g002 = fmaf(w2, b0, g002);
        g010 = fmaf(w0, b1, g010); g011 = fmaf(w1, b1, g011);
        g020 = fmaf(w0, b2, g020);
        g100 = fmaf(w0, b3, g100); g101 = fmaf(w1, b3, g101);
        g110 = fmaf(w0, b4, g110);
        g200 = fmaf(w0, b5, g200);
    }
    float mass = g000;
    float denom = (mass > 0.f) ? mass : 1.f;
    float inv = 1.f / denom;
    float p = g100 * inv, q = g010 * inv, s = g001 * inv;
    const float cs = 1.0f / 25.0f;                         // 1/sigma^2
    o[0] = 0.5f - 0.1f * p;                                // 1/(2 sigma) = 0.1
    o[1] = 0.5f - 0.1f * q;
    o[2] = 0.5f - 0.1f * s;
    o[3] = (g200 * inv - p * p) * cs;
    o[4] = (g020 * inv - q * q) * cs;
    o[5] = (g002 * inv - s * s) * cs;
    o[6] = (g110 * inv - p * q) * cs;
    o[7] = (g011 * inv - q * s) * cs;
    o[8] = (g101 * inv - p * s) * cs;
    o[9] = mass;
#pragma unroll
    for (int c = 0; c < 10; ++c) o[c] = fminf(fmaxf(o[c], 0.f), 1.f);
}

// -------- pass_yx8: A[lab][3] bf16 -> out. grid (2048, nlab), 128 thr. -----
// Tile = 8 rows (2z x 4y x 128x). Wave 0 = plane A0 (ch B0..B2); wave 1 =
// planes A1,A2 (ch B3..B5). Within a wave: bit5 = z-row, lanes cover 128 x
// as 32 x-groups of 4. Each thread computes T=4 y-outs for 3 channels at its
// (x-group, z-row): 12 fma4 per A0 load, no duplicated addresses.
// Compaction: ballot over contiguous 64-voxel spans (8 spans/wave) from a
// 1 KB seg LDS image -> x-consecutive list. Phase 2: per-lane 31-tap conv,
// direct f32 stores; zero-designated non-label voxels give full coverage.
template <typename ST>
__global__ __launch_bounds__(128) void pass_yx8(const unsigned short* __restrict__ A,
                                                const ST* __restrict__ seg,
                                                float* __restrict__ out,
                                                int label0, size_t a_stride,
                                                Kw kw) {
    __shared__ float4 kq4[40];                                 // {k0,k1,k2,0}[i-3]
    __shared__ __align__(16) unsigned short Bu[8 * RSTRIDE];   // 15,488 B
    __shared__ unsigned seg_l[256];                            // 1 KB tile seg
    __shared__ unsigned short lst[LCAP];                       // 1 KB
    __shared__ int cnt;

    // init: zero Bu (pads must be 0), weights, counter
    {
        uint4 z4 = make_uint4(0, 0, 0, 0);
        uint4* b4 = (uint4*)Bu;                            // 8*968/8 = 968
        for (int i = threadIdx.x; i < 968; i += 128) b4[i] = z4;
    }
    if (threadIdx.x < 40) {
        int i = threadIdx.x, j = i - 3; bool ok = (j >= 0) && (j < KL);
        kq4[i] = make_float4(ok ? kw.k0[j] : 0.f, ok ? kw.k1[j] : 0.f,
                             ok ? kw.k2[j] : 0.f, 0.f);
    }
    if (threadIdx.x == 0) cnt = 0;

    const int label = label0 + blockIdx.y;
    const unsigned short* Ab0 = A + (size_t)blockIdx.y * a_stride;
    const unsigned short* Ab1 = Ab0 + NV;
    const unsigned short* Ab2 = Ab0 + 2 * NV;

    const int h = blockIdx.x, g = h & 7, l = h >> 3;       // 2048 tiles
    const int z0 = 16 * g + 2 * (l & 7);                   // XCD g owns z slab
    const int y0 = (l >> 3) * 4;                           // 32 y-tiles

    // seg image for this tile: quad q covers voxels 4q..4q+3 (v = rr*128+x)
    {
#pragma unroll
        for (int q = threadIdx.x; q < 256; q += 128) {
            const int rr = q >> 5;                         // 0..7
            const int gb = ((z0 + (rr >> 2)) * 128 + (y0 + (rr & 3))) * 128 +
                           4 * (q & 31);
            seg_l[q] = seg_pack4(seg + gb);
        }
    }

    // roles
    const int lane = threadIdx.x & 63;
    const int w = threadIdx.x >> 6;                        // wave: 0=A0, 1=A1+A2
    const int lx = lane & 31;
    const int zr = lane >> 5;                              // z-row within tile
    const int x0 = 4 * lx;                                 // u16 elements
    const int zrs = (z0 + zr) * SLICE;
    const unsigned long long below_mask = (1ull << lane) - 1ull;

    __syncthreads();                                       // kq4 + seg_l ready

    // ---- phase 1: y-conv, T=4 outs, 3 channels per wave, 2-deep pipe ----
    float4 acc[3][4];                                      // [local ch][t]
#pragma unroll
    for (int c = 0; c < 3; ++c)
#pragma unroll
        for (int t = 0; t < 4; ++t) acc[c][t] = make_float4(0.f, 0.f, 0.f, 0.f);

    uint2 c1 = make_uint2(0u, 0u), n1 = c1, f1 = c1;       // A0 or A1
    uint2 c2 = c1, n2 = c1, f2 = c1;                       // A2 (wave 1 only)
    {
        int yy = y0 - R;
        if ((unsigned)yy < 128u) {
            int base = zrs + yy * 128 + x0;
            if (w == 0) c1 = *(const uint2*)(Ab0 + base);
            else { c1 = *(const uint2*)(Ab1 + base); c2 = *(const uint2*)(Ab2 + base); }
        }
        int yn = y0 + 1 - R;
        if ((unsigned)yn < 128u) {
            int base = zrs + yn * 128 + x0;
            if (w == 0) n1 = *(const uint2*)(Ab0 + base);
            else { n1 = *(const uint2*)(Ab1 + base); n2 = *(const uint2*)(Ab2 + base); }
        }
    }
    for (int j = 0; j < 34; ++j) {
        f1 = make_uint2(0u, 0u); f2 = f1;
        int yy = y0 + j + 2 - R;
        if (j < 32 && (unsigned)yy < 128u) {
            int base = zrs + yy * 128 + x0;
            if (w == 0) f1 = *(const uint2*)(Ab0 + base);
            else { f1 = *(const uint2*)(Ab1 + base); f2 = *(const uint2*)(Ab2 + base); }
        }
        if (w == 0) {
            float4 a0 = bf4_to_f4(c1);
#pragma unroll
            for (int t = 0; t < 4; ++t) {
                float4 wv = kq4[j + 3 - t];
                fma4(acc[0][t], wv.x, a0);                 // B0 = k0*A0
                fma4(acc[1][t], wv.y, a0);                 // B1 = k1*A0
                fma4(acc[2][t], wv.z, a0);                 // B2 = k2*A0
            }
        } else {
            float4 a1 = bf4_to_f4(c1), a2 = bf4_to_f4(c2);
#pragma unroll
            for (int t = 0; t < 4; ++t) {
                float4 wv = kq4[j + 3 - t];
                fma4(acc[0][t], wv.x, a1);                 // B3 = k0*A1
                fma4(acc[1][t], wv.y, a1);                 // B4 = k1*A1
                fma4(acc[2][t], wv.x, a2);                 // B5 = k0*A2
            }
        }
        c1 = n1; n1 = f1; c2 = n2; n2 = f2;
    }

    // ---- epilogue: write Bu; ballot-compact over contiguous spans ----
#pragma unroll
    for (int t = 0; t < 4; ++t) {
        const int row = zr * 4 + t;                        // row = 4*zsub + ysub
        const int cb = 3 * w;
#pragma unroll
        for (int c3 = 0; c3 < 3; ++c3) {
            float4 v = acc[c3][t];
            uint2 pv = make_uint2(pack_bf2(v.x, v.y), pack_bf2(v.z, v.w));
            *reinterpret_cast<uint2*>(Bu + row * RSTRIDE + (cb + c3) * CSTRIDE + 16 + x0) = pv;
        }
    }
    {
        const unsigned char* s8 = (const unsigned char*)seg_l;
#pragma unroll
        for (int s = 0; s < 8; ++s) {
            const int v = (w << 9) + (s << 6) + lane;      // contiguous span
            const int sv = (int)s8[v];
            const bool mt = (sv == label);
            const bool zt = !mt && (sv < 1 || sv > 8) && (((v & 7) + 1) == label);
            const bool pred = mt | zt;
            unsigned long long bal = __ballot(pred);
            int base = 0;
            if (lane == 0 && bal) base = atomicAdd(&cnt, (int)__popcll(bal));
            base = __shfl(base, 0);
            if (pred) {
                int pos = base + (int)__popcll(bal & below_mask);
                if (pos < LCAP)
                    lst[pos] = (unsigned short)(v | (zt ? 0x8000 : 0));
            }
        }
    }

    __syncthreads();                                       // Bu + lst + cnt

    // ---- phase 2: sparse x-conv + direct f32 stores ----
    const int total = cnt;
    if (total <= LCAP) {
        for (int e = threadIdx.x; e < total; e += 128) {
            int ent = lst[e];
            int v = ent & 1023, rr = v >> 7, x = v & 127;
            const int gb = ((z0 + (rr >> 2)) * 128 + (y0 + (rr & 3))) * 128 + x;
            if (ent & 0x8000) {
#pragma unroll
                for (int c = 0; c < 10; ++c) out[(size_t)c * NV + gb] = 0.f;
            } else {
                float o[10];
                conv_voxel(Bu, rr, x, kw, o);
#pragma unroll
                for (int c = 0; c < 10; ++c) out[(size_t)c * NV + gb] = o[c];
            }
        }
    } else {
        // adversarial-density fallback: each thread sweeps 8 voxels
        const unsigned char* s8 = (const unsigned char*)seg_l;
#pragma unroll
        for (int k = 0; k < 8; ++k) {
            const int v = 8 * (int)threadIdx.x + k;
            const int sv = (int)s8[v];
            const int rr = v >> 7, x = v & 127;
            const int gb = ((z0 + (rr >> 2)) * 128 + (y0 + (rr & 3))) * 128 + x;
            if (sv == label) {
                float o[10];
                conv_voxel(Bu, rr, x, kw, o);
#pragma unroll
                for (int c = 0; c < 10; ++c) out[(size_t)c * NV + gb] = o[c];
            } else if ((sv < 1 || sv > 8) && (((v & 7) + 1) == label)) {
#pragma unroll
                for (int c = 0; c < 10; ++c) out[(size_t)c * NV + gb] = 0.f;
            }
        }
    }
}

__global__ __launch_bounds__(256) void seg_to_u8(const int* __restrict__ seg,
                                                 unsigned char* __restrict__ seg8) {
    const int t = blockIdx.x * 256 + threadIdx.x;          // 2048 blocks
    const int4 s = ((const int4*)seg)[t];
    ((uchar4*)seg8)[t] = make_uchar4((unsigned char)s.x, (unsigned char)s.y,
                                     (unsigned char)s.z, (unsigned char)s.w);
}

extern "C" void kernel_launch(void* const* d_in, const int* in_sizes, int n_in,
                              void* d_out, int out_size, void* d_ws, size_t ws_size,
                              hipStream_t stream) {
    const int* seg = (const int*)d_in[0];
    // d_in[1] (coords) unused: math is translation-invariant.
    float* out = (float*)d_out;
    unsigned short* A = (unsigned short*)d_ws;             // bf16 A planes
    const size_t AVOL = (size_t)3 * NV;                    // u16 elements/label

    Kw kw;
    double gg[KL], S = 0.0;
    for (int j = 0; j < KL; ++j) { double d = j - R; gg[j] = exp(-0.5 * d * d / 25.0); S += gg[j]; }
    for (int j = 0; j < KL; ++j) {
        double gn = gg[j] / S, d = j - R;
        kw.k0[j] = (float)gn;
        kw.k1[j] = (float)(-d * gn);   // conv kernel k1 evaluated at (Z - t) = -d
        kw.k2[j] = (float)(d * d * gn);
    }

    // No memset: every output voxel is written exactly once across labels.

    const size_t need_all = 8 * AVOL * sizeof(unsigned short) + NV;  // A_all + seg8
    const size_t need_one = AVOL * sizeof(unsigned short) + NV;

    if (ws_size >= need_all) {
        // 3-dispatch path: labels batched in blockIdx.y, tile-major in x.
        unsigned char* seg8 = (unsigned char*)d_ws + 8 * AVOL * sizeof(unsigned short);
        seg_to_u8<<<dim3(2048), dim3(256), 0, stream>>>(seg, seg8);
        pass_z_t<unsigned char><<<dim3(512, 8), dim3(256), 0, stream>>>(
            seg8, A, 1, AVOL, kw);
        pass_yx8<unsigned char><<<dim3(2048, 8), dim3(128), 0, stream>>>(
            A, seg8, out, 1, AVOL, kw);
    } else if (ws_size >= need_one) {
        unsigned char* seg8 = (unsigned char*)d_ws + AVOL * sizeof(unsigned short);
        seg_to_u8<<<dim3(2048), dim3(256), 0, stream>>>(seg, seg8);
        for (int label = 1; label <= 8; ++label) {
            pass_z_t<unsigned char><<<dim3(512, 1), dim3(256), 0, stream>>>(
                seg8, A, label, 0, kw);
            pass_yx8<unsigned char><<<dim3(2048, 1), dim3(128), 0, stream>>>(
                A, seg8, out, label, 0, kw);
        }
    } else {
        for (int label = 1; label <= 8; ++label) {
            pass_z_t<int><<<dim3(512, 1), dim3(256), 0, stream>>>(
                seg, A, label, 0, kw);
            pass_yx8<int><<<dim3(2048, 1), dim3(128), 0, stream>>>(
                A, seg, out, label, 0, kw);
        }
    }
}

// Round 8
// 408.778 us; speedup vs baseline: 1.5750x; 1.0584x over previous
//
#include <hip/hip_runtime.h>
#include <hip/hip_fp16.h>
#include <math.h>

// LSD (local shape descriptors), 128^3, 8 labels, sigma=5, truncate=3 -> 31-tap kernel.
//
// Algebra: for label mask m, define G_{abc} = (k_a *_z)(k_b *_y)(k_c *_x) m with
//   k0(u)=w(u), k1(u)=u w(u), k2(u)=u^2 w(u)  (w = normalized gaussian).
// At a voxel with mass=G000>0, p=G100/mass, q=G010/mass, s=G001/mass:
//   mean_offset = 0.5 - {p,q,s}/(2 sigma);  cov_ab = (G../mass - ..)/sigma^2.
// Translation-invariant: coords input not needed. Masks disjoint.
//
// R8:  sparse phase 2 (LDS list): 487.
// R10: bf16 A + tile-major grid (1024,8): 412. FETCH 61 MB. latency/issue-bound.
// R11: 2-deep pipes + ballot compaction: 407 (pass_yx 289, VALU 46%, occ 21%).
//      BEST so far.
// R12-R14: block-owns-8-labels experiments: all worse (452/644/488). Lessons:
//      staging tax, launch-bounds spills, duplicated loads.
// R15: 8-row tile, 2x occupancy (32%): pass_yx8 313 -- SLOWER than R11.
//      CONCLUSION across R9-R15: occupancy never correlated with speedup;
//      instruction count did. => revert to R11 geometry, cut issue count.
// R16 (this round): phase-2 instruction diet on the exact R11 skeleton.
//   a) channel-INTERLEAVED Bu [row][tap][6ch] f16: one tap's 6 channels are
//      12 contiguous bytes -> 3x ds_read_b32 replaces 6x ds_read_u16
//      (4B-aligned: tap stride 12B, (x+1)*6 even; lane word-stride 3 ->
//      gcd(3,32)=1 conflict-free). 186 -> 93 reads/voxel.
//   b) f16 (not bf16) for A and Bu: unpack = v_cvt_f32_f16, and LLVM's
//      fma-mix combiner can fold fmaf(w, half2float(h), g) into
//      v_fma_mix_f32 (removes the 6 converts/tap too). f16 also has 2 more
//      mantissa bits (range needed <= 25) -> absmax should drop.
//   Geometry, compaction, stores, pass_z structure: R11-identical.
//   LDS = 30976(Bu) + 640(kq4) + 1024(lst) + 4 = 32644 <= 32KB -> 5 blk/CU.

constexpr int NV = 128 * 128 * 128;
constexpr int SLICE = 128 * 128;
constexpr int R = 15;
constexpr int KL = 31;
constexpr int TS = 6;                    // u16 per tap (6 interleaved channels)
constexpr int RSTRIDE = 160 * TS + 8;    // 968 u16 per row (16+128+16 taps + pad)
constexpr int LCAP = 512;

struct Kw { float k0[KL]; float k1[KL]; float k2[KL]; };

__device__ __forceinline__ void fma4(float4& a, float w, const float4& b) {
    a.x = fmaf(w, b.x, a.x); a.y = fmaf(w, b.y, a.y);
    a.z = fmaf(w, b.z, a.z); a.w = fmaf(w, b.w, a.w);
}

__device__ __forceinline__ float4 load_mask4(const unsigned char* p, int lab) {
    unsigned int u = *(const unsigned int*)p;
    return make_float4(((u       ) & 255u) == (unsigned)lab ? 1.f : 0.f,
                       ((u >>  8 ) & 255u) == (unsigned)lab ? 1.f : 0.f,
                       ((u >> 16 ) & 255u) == (unsigned)lab ? 1.f : 0.f,
                       ((u >> 24 ) & 255u) == (unsigned)lab ? 1.f : 0.f);
}
__device__ __forceinline__ float4 load_mask4(const int* p, int lab) {
    int4 s = *(const int4*)p;
    return make_float4(s.x == lab ? 1.f : 0.f, s.y == lab ? 1.f : 0.f,
                       s.z == lab ? 1.f : 0.f, s.w == lab ? 1.f : 0.f);
}

__device__ __forceinline__ unsigned seg_pack4(const unsigned char* p) {
    return *(const unsigned int*)p;
}
__device__ __forceinline__ unsigned seg_pack4(const int* p) {
    int4 v = *(const int4*)p;
    return (unsigned)(v.x & 255) | ((unsigned)(v.y & 255) << 8) |
           ((unsigned)(v.z & 255) << 16) | ((unsigned)(v.w & 255) << 24);
}

// ---- f16 helpers ----
__device__ __forceinline__ unsigned pack_h2(float a, float b) {
    __half2 h = __float22half2_rn(make_float2(a, b));
    return *reinterpret_cast<unsigned*>(&h);
}
__device__ __forceinline__ float h_lo(unsigned u) {
    return __half2float(__ushort_as_half((unsigned short)(u & 0xffffu)));
}
__device__ __forceinline__ float h_hi(unsigned u) {
    return __half2float(__ushort_as_half((unsigned short)(u >> 16)));
}
__device__ __forceinline__ float4 h4_to_f4(uint2 u) {
    return make_float4(h_lo(u.x), h_hi(u.x), h_lo(u.y), h_hi(u.y));
}

// -------- pass_z: seg -> A[lab][3] f16 (z-conv). grid (512, nlab), 256 thr.
template <typename ST>
__global__ __launch_bounds__(256) void pass_z_t(const ST* __restrict__ seg,
                                                unsigned short* __restrict__ A,
                                                int label0, size_t a_stride,
                                                Kw kw) {
    __shared__ float kp[3][37];           // zero-padded: kp[c][i] = k_c[i-3]
    if (threadIdx.x < 37) {
        int i = threadIdx.x, j = i - 3; bool ok = (j >= 0) && (j < KL);
        kp[0][i] = ok ? kw.k0[j] : 0.f;
        kp[1][i] = ok ? kw.k1[j] : 0.f;
        kp[2][i] = ok ? kw.k2[j] : 0.f;
    }
    __syncthreads();
    const int label = label0 + blockIdx.y;
    unsigned short* Ab = A + (size_t)blockIdx.y * a_stride;
    const int h = blockIdx.x, g = h & 7, l = h >> 3;       // 512 x-blocks
    const int tx = threadIdx.x & 31, ty = threadIdx.x >> 5;
    const int x0 = tx * 4;
    const int z0 = 16 * g + 4 * (l & 3);                   // XCD g owns z [16g,16g+16)
    const int y  = (l >> 2) * 8 + ty;

    float4 acc[4][3];
#pragma unroll
    for (int t = 0; t < 4; ++t)
#pragma unroll
        for (int c = 0; c < 3; ++c) acc[t][c] = make_float4(0.f, 0.f, 0.f, 0.f);

    // 2-deep pipelined sliding window: load j+2 while FMAing j.
    float4 cm = make_float4(0.f, 0.f, 0.f, 0.f), nm = cm;
    {
        int zz = z0 - R;
        if ((unsigned)zz < 128u)
            cm = load_mask4(seg + (zz * SLICE + y * 128 + x0), label);
        int zn = z0 + 1 - R;
        if ((unsigned)zn < 128u)
            nm = load_mask4(seg + (zn * SLICE + y * 128 + x0), label);
    }
    for (int j = 0; j < 34; ++j) {                         // window: 4 outs + 30
        float4 fm = make_float4(0.f, 0.f, 0.f, 0.f);
        int zz = z0 + j + 2 - R;                           // uniform per wave
        if (j < 32 && (unsigned)zz < 128u)
            fm = load_mask4(seg + (zz * SLICE + y * 128 + x0), label);
#pragma unroll
        for (int t = 0; t < 4; ++t) {
            int i = j - t + 3;                             // padded weight index
            fma4(acc[t][0], kp[0][i], cm);
            fma4(acc[t][1], kp[1][i], cm);
            fma4(acc[t][2], kp[2][i], cm);
        }
        cm = nm; nm = fm;
    }
#pragma unroll
    for (int t = 0; t < 4; ++t) {
        int base = (z0 + t) * SLICE + y * 128 + x0;
#pragma unroll
        for (int c = 0; c < 3; ++c) {
            float4 v = acc[t][c];
            uint2 pv = make_uint2(pack_h2(v.x, v.y), pack_h2(v.z, v.w));
            *reinterpret_cast<uint2*>(Ab + (size_t)c * NV + base) = pv;
        }
    }
}

// ---- per-voxel sparse x-conv (interleaved f16 Bu rows, zero-padded) ----
// Bu value (row, tap u, ch c) at u16 index row*RSTRIDE + u*6 + c.
// Window tap j reads u = x+1+j in [1,159); (x+1)*6 even -> 4B-aligned u32s.
__device__ __forceinline__ void conv_voxel(const unsigned short* __restrict__ Bu,
                                           int rr, int x, const Kw& kw,
                                           float o[10]) {
    const unsigned short* row = Bu + rr * RSTRIDE + (x + 1) * TS;
    float g000 = 0, g001 = 0, g002 = 0, g010 = 0, g011 = 0,
          g020 = 0, g100 = 0, g101 = 0, g110 = 0, g200 = 0;
#pragma unroll
    for (int j = 0; j < KL; ++j) {
        const unsigned* p = (const unsigned*)(row + TS * j);
        unsigned ua = p[0], ub = p[1], uc = p[2];          // {B0,B1}{B2,B3}{B4,B5}
        float w0 = kw.k0[j], w1 = kw.k1[j], w2 = kw.k2[j];
        float b0 = h_lo(ua), b1 = h_hi(ua);
        float b2 = h_lo(ub), b3 = h_hi(ub);
        float b4 = h_lo(uc), b5 = h_hi(uc);
        g000 = fmaf(w0, b0, g000); g001 = fmaf(w1, b0, g001); g002 = fmaf(w2, b0, g002);
        g010 = fmaf(w0, b1, g010); g011 = fmaf(w1, b1, g011);
        g020 = fmaf(w0, b2, g020);
        g100 = fmaf(w0, b3, g100); g101 = fmaf(w1, b3, g101);
        g110 = fmaf(w0, b4, g110);
        g200 = fmaf(w0, b5, g200);
    }
    float mass = g000;
    float denom = (mass > 0.f) ? mass : 1.f;
    float inv = 1.f / denom;
    float p = g100 * inv, q = g010 * inv, s = g001 * inv;
    const float cs = 1.0f / 25.0f;                         // 1/sigma^2
    o[0] = 0.5f - 0.1f * p;                                // 1/(2 sigma) = 0.1
    o[1] = 0.5f - 0.1f * q;
    o[2] = 0.5f - 0.1f * s;
    o[3] = (g200 * inv - p * p) * cs;
    o[4] = (g020 * inv - q * q) * cs;
    o[5] = (g002 * inv - s * s) * cs;
    o[6] = (g110 * inv - p * q) * cs;
    o[7] = (g011 * inv - q * s) * cs;
    o[8] = (g101 * inv - p * s) * cs;
    o[9] = mass;
#pragma unroll
    for (int c = 0; c < 10; ++c) o[c] = fminf(fmaxf(o[c], 0.f), 1.f);
}

__device__ __forceinline__ void do_voxel_out(const unsigned short* __restrict__ Bu,
                                             int rr, int x, int z0, int y0,
                                             float* __restrict__ out, const Kw& kw) {
    float o[10];
    conv_voxel(Bu, rr, x, kw, o);
    const int z2 = z0 + (rr >> 2), y2 = y0 + (rr & 3);
    const int v = (z2 * 128 + y2) * 128 + x;
#pragma unroll
    for (int c = 0; c < 10; ++c) out[(size_t)c * NV + v] = o[c];
}

__device__ __forceinline__ void zero_voxel(int rr, int x, int z0, int y0,
                                           float* __restrict__ out) {
    const int z2 = z0 + (rr >> 2), y2 = y0 + (rr & 3);
    const int v = (z2 * 128 + y2) * 128 + x;
#pragma unroll
    for (int c = 0; c < 10; ++c) out[(size_t)c * NV + v] = 0.f;
}

// -------- pass_yx: A[lab][3] f16 -> out. grid (1024, nlab), 128 thr. -------
// R11 geometry: 16-row tile (4z x 4y), T=4 sliding y-outs, 2-deep pipeline.
// Phase-1 output -> channel-interleaved f16 Bu. Ballot compaction (register
// pk). Phase 2: sparse per-voxel conv + direct f32 stores; zero-designated
// non-label voxels give full coverage (no memset).
template <typename ST>
__global__ __launch_bounds__(128) void pass_yx(const unsigned short* __restrict__ A,
                                               const ST* __restrict__ seg,
                                               float* __restrict__ out,
                                               int label0, size_t a_stride,
                                               Kw kw) {
    __shared__ float4 kq4[40];                                 // {k0,k1,k2,0}[i-3]
    __shared__ __align__(16) unsigned short Bu[16 * RSTRIDE];  // 30,976 B
    __shared__ unsigned short lst[LCAP];                       // 1 KB
    __shared__ int cnt;

    // zero Bu (pads must be exactly 0) + weights + counter
    {
        uint4 z4 = make_uint4(0, 0, 0, 0);
        uint4* b4 = (uint4*)Bu;                            // 16*968*2/16 = 1936
        for (int i = threadIdx.x; i < 1936; i += 128) b4[i] = z4;
    }
    if (threadIdx.x < 40) {
        int i = threadIdx.x, j = i - 3; bool ok = (j >= 0) && (j < KL);
        kq4[i] = make_float4(ok ? kw.k0[j] : 0.f, ok ? kw.k1[j] : 0.f,
                             ok ? kw.k2[j] : 0.f, 0.f);
    }
    if (threadIdx.x == 0) cnt = 0;
    __syncthreads();

    const int labi = blockIdx.y;
    const int label = label0 + labi;
    const unsigned short* Ab = A + (size_t)labi * a_stride;
    const int h = blockIdx.x, g = h & 7, l = h >> 3;       // 1024 x-blocks
    const int tx = threadIdx.x & 31, tz = threadIdx.x >> 5; // tz 0..3
    const int x0 = tx * 4;
    const int z0 = 16 * g + 4 * (l & 3);                   // XCD g owns z slab
    const int y0 = (l >> 2) * 4;                           // 32 y-tiles
    const int zs = (z0 + tz) * SLICE;

    // pre-issue compaction seg loads (complete under phase 1)
    const int rr_c = threadIdx.x >> 3, q0_c = threadIdx.x & 7;
    const int vrow_c = ((z0 + (rr_c >> 2)) * 128 + (y0 + (rr_c & 3))) * 128;
    unsigned pk[4];
#pragma unroll
    for (int k = 0; k < 4; ++k)
        pk[k] = seg_pack4(seg + vrow_c + 4 * (q0_c + 8 * k));

    // ---- phase 1: y-conv, T=4 outputs sliding in registers, 2-deep pipe ----
    float4 acc[6][4];                                      // [ch][t]
#pragma unroll
    for (int c = 0; c < 6; ++c)
#pragma unroll
        for (int t = 0; t < 4; ++t) acc[c][t] = make_float4(0.f, 0.f, 0.f, 0.f);

    uint2 c0 = make_uint2(0u, 0u), c1 = c0, c2 = c0;       // packed f16 x4
    uint2 n0 = c0, n1 = c0, n2 = c0;
    {
        int yy = y0 - R;
        if ((unsigned)yy < 128u) {
            int base = zs + yy * 128 + x0;
            c0 = *(const uint2*)(Ab + base);
            c1 = *(const uint2*)(Ab + NV + base);
            c2 = *(const uint2*)(Ab + 2 * NV + base);
        }
        int yn = y0 + 1 - R;
        if ((unsigned)yn < 128u) {
            int base = zs + yn * 128 + x0;
            n0 = *(const uint2*)(Ab + base);
            n1 = *(const uint2*)(Ab + NV + base);
            n2 = *(const uint2*)(Ab + 2 * NV + base);
        }
    }
    for (int j = 0; j < 34; ++j) {
        uint2 f0 = make_uint2(0u, 0u), f1 = f0, f2 = f0;
        int yy = y0 + j + 2 - R;
        if (j < 32 && (unsigned)yy < 128u) {
            int base = zs + yy * 128 + x0;
            f0 = *(const uint2*)(Ab + base);
            f1 = *(const uint2*)(Ab + NV + base);
            f2 = *(const uint2*)(Ab + 2 * NV + base);
        }
        float4 a0 = h4_to_f4(c0), a1 = h4_to_f4(c1), a2 = h4_to_f4(c2);
#pragma unroll
        for (int t = 0; t < 4; ++t) {
            float4 wv = kq4[j + 3 - t];
            fma4(acc[0][t], wv.x, a0);
            fma4(acc[1][t], wv.y, a0);
            fma4(acc[2][t], wv.z, a0);
            fma4(acc[3][t], wv.x, a1);
            fma4(acc[4][t], wv.y, a1);
            fma4(acc[5][t], wv.x, a2);
        }
        c0 = n0; c1 = n1; c2 = n2;
        n0 = f0; n1 = f1; n2 = f2;
    }

    // ---- epilogue: write interleaved Bu rows ----
#pragma unroll
    for (int t = 0; t < 4; ++t) {
        const int row = tz * 4 + t;                        // row = 4*zsub + ysub
        unsigned short* rbase = Bu + row * RSTRIDE + (16 + x0) * TS;
#pragma unroll
        for (int xi = 0; xi < 4; ++xi) {
            unsigned* w32 = (unsigned*)(rbase + xi * TS);
            float v0 = (&acc[0][t].x)[xi], v1 = (&acc[1][t].x)[xi];
            float v2 = (&acc[2][t].x)[xi], v3 = (&acc[3][t].x)[xi];
            float v4 = (&acc[4][t].x)[xi], v5 = (&acc[5][t].x)[xi];
            w32[0] = pack_h2(v0, v1);
            w32[1] = pack_h2(v2, v3);
            w32[2] = pack_h2(v4, v5);
        }
    }

    // ---- compaction: ballot-based, 1 atomic per wave per step ----
    {
        const int lane = threadIdx.x & 63;
        const unsigned long long below_mask = (1ull << lane) - 1ull;
#pragma unroll
        for (int k = 0; k < 4; ++k) {
            const unsigned w = pk[k];
#pragma unroll
            for (int t = 0; t < 4; ++t) {
                const int sv = (int)((w >> (8 * t)) & 255u);
                const int x = 4 * (q0_c + 8 * k) + t;
                const bool mt = (sv == label);
                const bool zt = !mt && (sv < 1 || sv > 8) &&
                                (((x & 7) + 1) == label);
                const bool pred = mt | zt;
                unsigned long long bal = __ballot(pred);
                int base = 0;
                if (lane == 0 && bal) base = atomicAdd(&cnt, (int)__popcll(bal));
                base = __shfl(base, 0);
                if (pred) {
                    int pos = base + (int)__popcll(bal & below_mask);
                    if (pos < LCAP)
                        lst[pos] = (unsigned short)((rr_c << 7) | x | (zt ? 0x8000 : 0));
                }
            }
        }
    }

    __syncthreads();

    // ---- phase 2: sparse x-conv + epilogue (or zero-store) ----
    const int total = cnt;
    if (total <= LCAP) {
        for (int e = threadIdx.x; e < total; e += 128) {
            int ent = lst[e];
            int rr = (ent >> 7) & 15, x = ent & 127;
            if (ent & 0x8000) zero_voxel(rr, x, z0, y0, out);
            else do_voxel_out(Bu, rr, x, z0, y0, out, kw);
        }
    } else {
        // adversarial-density fallback: dense masked sweep (same math)
        for (int e = threadIdx.x; e < 2048; e += 128) {
            int rr = e >> 7, x = e & 127;
            int z2 = z0 + (rr >> 2), y2 = y0 + (rr & 3);
            int sv = (int)seg[(z2 * 128 + y2) * 128 + x] & 255;
            if (sv == label)
                do_voxel_out(Bu, rr, x, z0, y0, out, kw);
            else if ((sv < 1 || sv > 8) && (((x & 7) + 1) == label))
                zero_voxel(rr, x, z0, y0, out);
        }
    }
}

__global__ __launch_bounds__(256) void seg_to_u8(const int* __restrict__ seg,
                                                 unsigned char* __restrict__ seg8) {
    const int t = blockIdx.x * 256 + threadIdx.x;          // 2048 blocks
    const int4 s = ((const int4*)seg)[t];
    ((uchar4*)seg8)[t] = make_uchar4((unsigned char)s.x, (unsigned char)s.y,
                                     (unsigned char)s.z, (unsigned char)s.w);
}

extern "C" void kernel_launch(void* const* d_in, const int* in_sizes, int n_in,
                              void* d_out, int out_size, void* d_ws, size_t ws_size,
                              hipStream_t stream) {
    const int* seg = (const int*)d_in[0];
    // d_in[1] (coords) unused: math is translation-invariant.
    float* out = (float*)d_out;
    unsigned short* A = (unsigned short*)d_ws;             // f16 A planes
    const size_t AVOL = (size_t)3 * NV;                    // u16 elements/label

    Kw kw;
    double gg[KL], S = 0.0;
    for (int j = 0; j < KL; ++j) { double d = j - R; gg[j] = exp(-0.5 * d * d / 25.0); S += gg[j]; }
    for (int j = 0; j < KL; ++j) {
        double gn = gg[j] / S, d = j - R;
        kw.k0[j] = (float)gn;
        kw.k1[j] = (float)(-d * gn);   // conv kernel k1 evaluated at (Z - t) = -d
        kw.k2[j] = (float)(d * d * gn);
    }

    // No memset: every output voxel is written exactly once across labels.

    const size_t need_all = 8 * AVOL * sizeof(unsigned short) + NV;  // A_all + seg8
    const size_t need_one = AVOL * sizeof(unsigned short) + NV;

    if (ws_size >= need_all) {
        // 3-dispatch path: labels batched in blockIdx.y, tile-major in x.
        unsigned char* seg8 = (unsigned char*)d_ws + 8 * AVOL * sizeof(unsigned short);
        seg_to_u8<<<dim3(2048), dim3(256), 0, stream>>>(seg, seg8);
        pass_z_t<unsigned char><<<dim3(512, 8), dim3(256), 0, stream>>>(
            seg8, A, 1, AVOL, kw);
        pass_yx<unsigned char><<<dim3(1024, 8), dim3(128), 0, stream>>>(
            A, seg8, out, 1, AVOL, kw);
    } else if (ws_size >= need_one) {
        unsigned char* seg8 = (unsigned char*)d_ws + AVOL * sizeof(unsigned short);
        seg_to_u8<<<dim3(2048), dim3(256), 0, stream>>>(seg, seg8);
        for (int label = 1; label <= 8; ++label) {
            pass_z_t<unsigned char><<<dim3(512, 1), dim3(256), 0, stream>>>(
                seg8, A, label, 0, kw);
            pass_yx<unsigned char><<<dim3(1024, 1), dim3(128), 0, stream>>>(
                A, seg8, out, label, 0, kw);
        }
    } else {
        for (int label = 1; label <= 8; ++label) {
            pass_z_t<int><<<dim3(512, 1), dim3(256), 0, stream>>>(
                seg, A, label, 0, kw);
            pass_yx<int><<<dim3(1024, 1), dim3(128), 0, stream>>>(
                A, seg, out, label, 0, kw);
        }
    }
}

// Round 9
// 404.929 us; speedup vs baseline: 1.5899x; 1.0095x over previous
//
#include <hip/hip_runtime.h>
#include <hip/hip_fp16.h>
#include <math.h>

// LSD (local shape descriptors), 128^3, 8 labels, sigma=5, truncate=3 -> 31-tap kernel.
//
// Algebra: for label mask m, define G_{abc} = (k_a *_z)(k_b *_y)(k_c *_x) m with
//   k0(u)=w(u), k1(u)=u w(u), k2(u)=u^2 w(u)  (w = normalized gaussian).
// At a voxel with mass=G000>0, p=G100/mass, q=G010/mass, s=G001/mass:
//   mean_offset = 0.5 - {p,q,s}/(2 sigma);  cov_ab = (G../mass - ..)/sigma^2.
// Translation-invariant: coords input not needed. Masks disjoint.
//
// R11: 2-deep pipes + ballot compaction: 407 total (pass_yx 289, conflicts
//      810K). Best plain-layout version.
// R12-R15: occupancy experiments all refuted: occupancy never correlated
//      with speedup; instruction count did.
// R16: channel-interleaved f16 Bu (3x ds_read_b32/tap replaces 6x u16) BUT
//      kept R11's x-stride-4 compaction order -> lane byte-stride 48 ->
//      8-way conflicts on EVERY phase-2 read and epilogue write:
//      conflicts 810K -> 15.1M, pass_yx 289 -> 313. Layout was right,
//      access ORDER was wrong.
// R17 (this round): same layout, conflict-free order.
//   a) span-contiguous compaction (R15 technique): seg bytes staged in a
//      2 KB LDS image (from the preloaded pk regs), ballot over 32
//      contiguous 64-voxel spans -> list entries x-consecutive -> phase-2
//      lane word-stride 3, gcd(3,32)=1 -> conflict-free.
//   b) epilogue: each thread's 4 x-positions x 6 ch = 48 contiguous
//      16B-aligned bytes -> 3x ds_write_b128 per row (12 instead of 48
//      write instrs), uniform bank spread.
//   c) extra __syncthreads() before compaction (seg_l cross-thread reads).
//   LDS 34,692 B -> still 4 blk/CU. Geometry/stores/pass_z: R11-identical.

constexpr int NV = 128 * 128 * 128;
constexpr int SLICE = 128 * 128;
constexpr int R = 15;
constexpr int KL = 31;
constexpr int TS = 6;                    // u16 per tap (6 interleaved channels)
constexpr int RSTRIDE = 160 * TS + 8;    // 968 u16 per row (16+128+16 taps + pad)
constexpr int LCAP = 512;

struct Kw { float k0[KL]; float k1[KL]; float k2[KL]; };

__device__ __forceinline__ void fma4(float4& a, float w, const float4& b) {
    a.x = fmaf(w, b.x, a.x); a.y = fmaf(w, b.y, a.y);
    a.z = fmaf(w, b.z, a.z); a.w = fmaf(w, b.w, a.w);
}

__device__ __forceinline__ float4 load_mask4(const unsigned char* p, int lab) {
    unsigned int u = *(const unsigned int*)p;
    return make_float4(((u       ) & 255u) == (unsigned)lab ? 1.f : 0.f,
                       ((u >>  8 ) & 255u) == (unsigned)lab ? 1.f : 0.f,
                       ((u >> 16 ) & 255u) == (unsigned)lab ? 1.f : 0.f,
                       ((u >> 24 ) & 255u) == (unsigned)lab ? 1.f : 0.f);
}
__device__ __forceinline__ float4 load_mask4(const int* p, int lab) {
    int4 s = *(const int4*)p;
    return make_float4(s.x == lab ? 1.f : 0.f, s.y == lab ? 1.f : 0.f,
                       s.z == lab ? 1.f : 0.f, s.w == lab ? 1.f : 0.f);
}

__device__ __forceinline__ unsigned seg_pack4(const unsigned char* p) {
    return *(const unsigned int*)p;
}
__device__ __forceinline__ unsigned seg_pack4(const int* p) {
    int4 v = *(const int4*)p;
    return (unsigned)(v.x & 255) | ((unsigned)(v.y & 255) << 8) |
           ((unsigned)(v.z & 255) << 16) | ((unsigned)(v.w & 255) << 24);
}

// ---- f16 helpers ----
__device__ __forceinline__ unsigned pack_h2(float a, float b) {
    __half2 h = __float22half2_rn(make_float2(a, b));
    return *reinterpret_cast<unsigned*>(&h);
}
__device__ __forceinline__ float h_lo(unsigned u) {
    return __half2float(__ushort_as_half((unsigned short)(u & 0xffffu)));
}
__device__ __forceinline__ float h_hi(unsigned u) {
    return __half2float(__ushort_as_half((unsigned short)(u >> 16)));
}
__device__ __forceinline__ float4 h4_to_f4(uint2 u) {
    return make_float4(h_lo(u.x), h_hi(u.x), h_lo(u.y), h_hi(u.y));
}

// -------- pass_z: seg -> A[lab][3] f16 (z-conv). grid (512, nlab), 256 thr.
template <typename ST>
__global__ __launch_bounds__(256) void pass_z_t(const ST* __restrict__ seg,
                                                unsigned short* __restrict__ A,
                                                int label0, size_t a_stride,
                                                Kw kw) {
    __shared__ float kp[3][37];           // zero-padded: kp[c][i] = k_c[i-3]
    if (threadIdx.x < 37) {
        int i = threadIdx.x, j = i - 3; bool ok = (j >= 0) && (j < KL);
        kp[0][i] = ok ? kw.k0[j] : 0.f;
        kp[1][i] = ok ? kw.k1[j] : 0.f;
        kp[2][i] = ok ? kw.k2[j] : 0.f;
    }
    __syncthreads();
    const int label = label0 + blockIdx.y;
    unsigned short* Ab = A + (size_t)blockIdx.y * a_stride;
    const int h = blockIdx.x, g = h & 7, l = h >> 3;       // 512 x-blocks
    const int tx = threadIdx.x & 31, ty = threadIdx.x >> 5;
    const int x0 = tx * 4;
    const int z0 = 16 * g + 4 * (l & 3);                   // XCD g owns z [16g,16g+16)
    const int y  = (l >> 2) * 8 + ty;

    float4 acc[4][3];
#pragma unroll
    for (int t = 0; t < 4; ++t)
#pragma unroll
        for (int c = 0; c < 3; ++c) acc[t][c] = make_float4(0.f, 0.f, 0.f, 0.f);

    // 2-deep pipelined sliding window: load j+2 while FMAing j.
    float4 cm = make_float4(0.f, 0.f, 0.f, 0.f), nm = cm;
    {
        int zz = z0 - R;
        if ((unsigned)zz < 128u)
            cm = load_mask4(seg + (zz * SLICE + y * 128 + x0), label);
        int zn = z0 + 1 - R;
        if ((unsigned)zn < 128u)
            nm = load_mask4(seg + (zn * SLICE + y * 128 + x0), label);
    }
    for (int j = 0; j < 34; ++j) {                         // window: 4 outs + 30
        float4 fm = make_float4(0.f, 0.f, 0.f, 0.f);
        int zz = z0 + j + 2 - R;                           // uniform per wave
        if (j < 32 && (unsigned)zz < 128u)
            fm = load_mask4(seg + (zz * SLICE + y * 128 + x0), label);
#pragma unroll
        for (int t = 0; t < 4; ++t) {
            int i = j - t + 3;                             // padded weight index
            fma4(acc[t][0], kp[0][i], cm);
            fma4(acc[t][1], kp[1][i], cm);
            fma4(acc[t][2], kp[2][i], cm);
        }
        cm = nm; nm = fm;
    }
#pragma unroll
    for (int t = 0; t < 4; ++t) {
        int base = (z0 + t) * SLICE + y * 128 + x0;
#pragma unroll
        for (int c = 0; c < 3; ++c) {
            float4 v = acc[t][c];
            uint2 pv = make_uint2(pack_h2(v.x, v.y), pack_h2(v.z, v.w));
            *reinterpret_cast<uint2*>(Ab + (size_t)c * NV + base) = pv;
        }
    }
}

// ---- per-voxel sparse x-conv (interleaved f16 Bu rows, zero-padded) ----
// Bu value (row, tap u, ch c) at u16 index row*RSTRIDE + u*6 + c.
// Window tap j reads u = x+1+j in [1,159); (x+1)*6 even -> 4B-aligned u32s.
// With x-consecutive lanes: lane word-stride 3 -> conflict-free.
__device__ __forceinline__ void conv_voxel(const unsigned short* __restrict__ Bu,
                                           int rr, int x, const Kw& kw,
                                           float o[10]) {
    const unsigned short* row = Bu + rr * RSTRIDE + (x + 1) * TS;
    float g000 = 0, g001 = 0, g002 = 0, g010 = 0, g011 = 0,
          g020 = 0, g100 = 0, g101 = 0, g110 = 0, g200 = 0;
#pragma unroll
    for (int j = 0; j < KL; ++j) {
        const unsigned* p = (const unsigned*)(row + TS * j);
        unsigned ua = p[0], ub = p[1], uc = p[2];          // {B0,B1}{B2,B3}{B4,B5}
        float w0 = kw.k0[j], w1 = kw.k1[j], w2 = kw.k2[j];
        float b0 = h_lo(ua), b1 = h_hi(ua);
        float b2 = h_lo(ub), b3 = h_hi(ub);
        float b4 = h_lo(uc), b5 = h_hi(uc);
        g000 = fmaf(w0, b0, g000); g001 = fmaf(w1, b0, g001); g002 = fmaf(w2, b0, g002);
        g010 = fmaf(w0, b1, g010); g011 = fmaf(w1, b1, g011);
        g020 = fmaf(w0, b2, g020);
        g100 = fmaf(w0, b3, g100); g101 = fmaf(w1, b3, g101);
        g110 = fmaf(w0, b4, g110);
        g200 = fmaf(w0, b5, g200);
    }
    float mass = g000;
    float denom = (mass > 0.f) ? mass : 1.f;
    float inv = 1.f / denom;
    float p = g100 * inv, q = g010 * inv, s = g001 * inv;
    const float cs = 1.0f / 25.0f;                         // 1/sigma^2
    o[0] = 0.5f - 0.1f * p;                                // 1/(2 sigma) = 0.1
    o[1] = 0.5f - 0.1f * q;
    o[2] = 0.5f - 0.1f * s;
    o[3] = (g200 * inv - p * p) * cs;
    o[4] = (g020 * inv - q * q) * cs;
    o[5] = (g002 * inv - s * s) * cs;
    o[6] = (g110 * inv - p * q) * cs;
    o[7] = (g011 * inv - q * s) * cs;
    o[8] = (g101 * inv - p * s) * cs;
    o[9] = mass;
#pragma unroll
    for (int c = 0; c < 10; ++c) o[c] = fminf(fmaxf(o[c], 0.f), 1.f);
}

__device__ __forceinline__ void do_voxel_out(const unsigned short* __restrict__ Bu,
                                             int rr, int x, int z0, int y0,
                                             float* __restrict__ out, const Kw& kw) {
    float o[10];
    conv_voxel(Bu, rr, x, kw, o);
    const int z2 = z0 + (rr >> 2), y2 = y0 + (rr & 3);
    const int v = (z2 * 128 + y2) * 128 + x;
#pragma unroll
    for (int c = 0; c < 10; ++c) out[(size_t)c * NV + v] = o[c];
}

__device__ __forceinline__ void zero_voxel(int rr, int x, int z0, int y0,
                                           float* __restrict__ out) {
    const int z2 = z0 + (rr >> 2), y2 = y0 + (rr & 3);
    const int v = (z2 * 128 + y2) * 128 + x;
#pragma unroll
    for (int c = 0; c < 10; ++c) out[(size_t)c * NV + v] = 0.f;
}

// -------- pass_yx: A[lab][3] f16 -> out. grid (1024, nlab), 128 thr. -------
// R11 geometry: 16-row tile (4z x 4y), T=4 sliding y-outs, 2-deep pipeline.
// Phase-1 output -> channel-interleaved f16 Bu (3x ds_write_b128 per row).
// Compaction: ballot over 32 contiguous 64-voxel spans from a 2 KB seg LDS
// image -> x-consecutive list. Phase 2: sparse conv + direct f32 stores;
// zero-designated non-label voxels give full coverage (no memset).
template <typename ST>
__global__ __launch_bounds__(128) void pass_yx(const unsigned short* __restrict__ A,
                                               const ST* __restrict__ seg,
                                               float* __restrict__ out,
                                               int label0, size_t a_stride,
                                               Kw kw) {
    __shared__ float4 kq4[40];                                 // {k0,k1,k2,0}[i-3]
    __shared__ __align__(16) unsigned short Bu[16 * RSTRIDE];  // 30,976 B
    __shared__ unsigned seg_l[512];                            // 2 KB tile seg bytes
    __shared__ unsigned short lst[LCAP];                       // 1 KB
    __shared__ int cnt;

    // zero Bu (pads must be exactly 0) + weights + counter
    {
        uint4 z4 = make_uint4(0, 0, 0, 0);
        uint4* b4 = (uint4*)Bu;                            // 16*968*2/16 = 1936
        for (int i = threadIdx.x; i < 1936; i += 128) b4[i] = z4;
    }
    if (threadIdx.x < 40) {
        int i = threadIdx.x, j = i - 3; bool ok = (j >= 0) && (j < KL);
        kq4[i] = make_float4(ok ? kw.k0[j] : 0.f, ok ? kw.k1[j] : 0.f,
                             ok ? kw.k2[j] : 0.f, 0.f);
    }
    if (threadIdx.x == 0) cnt = 0;
    __syncthreads();

    const int labi = blockIdx.y;
    const int label = label0 + labi;
    const unsigned short* Ab = A + (size_t)labi * a_stride;
    const int h = blockIdx.x, g = h & 7, l = h >> 3;       // 1024 x-blocks
    const int tx = threadIdx.x & 31, tz = threadIdx.x >> 5; // tz 0..3
    const int x0 = tx * 4;
    const int z0 = 16 * g + 4 * (l & 3);                   // XCD g owns z slab
    const int y0 = (l >> 2) * 4;                           // 32 y-tiles
    const int zs = (z0 + tz) * SLICE;

    // pre-issue seg loads; stage into LDS image seg_l[row*32 + x/4]
    // (visible to all threads after the pre-compaction barrier)
    {
        const int rr_c = threadIdx.x >> 3, q0_c = threadIdx.x & 7;
        const int vrow_c = ((z0 + (rr_c >> 2)) * 128 + (y0 + (rr_c & 3))) * 128;
#pragma unroll
        for (int k = 0; k < 4; ++k) {
            unsigned pkv = seg_pack4(seg + vrow_c + 4 * (q0_c + 8 * k));
            seg_l[rr_c * 32 + q0_c + 8 * k] = pkv;
        }
    }

    // ---- phase 1: y-conv, T=4 outputs sliding in registers, 2-deep pipe ----
    float4 acc[6][4];                                      // [ch][t]
#pragma unroll
    for (int c = 0; c < 6; ++c)
#pragma unroll
        for (int t = 0; t < 4; ++t) acc[c][t] = make_float4(0.f, 0.f, 0.f, 0.f);

    uint2 c0 = make_uint2(0u, 0u), c1 = c0, c2 = c0;       // packed f16 x4
    uint2 n0 = c0, n1 = c0, n2 = c0;
    {
        int yy = y0 - R;
        if ((unsigned)yy < 128u) {
            int base = zs + yy * 128 + x0;
            c0 = *(const uint2*)(Ab + base);
            c1 = *(const uint2*)(Ab + NV + base);
            c2 = *(const uint2*)(Ab + 2 * NV + base);
        }
        int yn = y0 + 1 - R;
        if ((unsigned)yn < 128u) {
            int base = zs + yn * 128 + x0;
            n0 = *(const uint2*)(Ab + base);
            n1 = *(const uint2*)(Ab + NV + base);
            n2 = *(const uint2*)(Ab + 2 * NV + base);
        }
    }
    for (int j = 0; j < 34; ++j) {
        uint2 f0 = make_uint2(0u, 0u), f1 = f0, f2 = f0;
        int yy = y0 + j + 2 - R;
        if (j < 32 && (unsigned)yy < 128u) {
            int base = zs + yy * 128 + x0;
            f0 = *(const uint2*)(Ab + base);
            f1 = *(const uint2*)(Ab + NV + base);
            f2 = *(const uint2*)(Ab + 2 * NV + base);
        }
        float4 a0 = h4_to_f4(c0), a1 = h4_to_f4(c1), a2 = h4_to_f4(c2);
#pragma unroll
        for (int t = 0; t < 4; ++t) {
            float4 wv = kq4[j + 3 - t];
            fma4(acc[0][t], wv.x, a0);
            fma4(acc[1][t], wv.y, a0);
            fma4(acc[2][t], wv.z, a0);
            fma4(acc[3][t], wv.x, a1);
            fma4(acc[4][t], wv.y, a1);
            fma4(acc[5][t], wv.x, a2);
        }
        c0 = n0; c1 = n1; c2 = n2;
        n0 = f0; n1 = f1; n2 = f2;
    }

    // ---- epilogue: this thread's 4 x-positions x 6 ch = 48 contiguous
    //      16B-aligned bytes -> 3x ds_write_b128 per row ----
#pragma unroll
    for (int t = 0; t < 4; ++t) {
        const int row = tz * 4 + t;                        // row = 4*zsub + ysub
        uint4* w128 = (uint4*)(Bu + row * RSTRIDE + (16 + x0) * TS);
        uint4 wa, wb, wc;
        wa.x = pack_h2(acc[0][t].x, acc[1][t].x);
        wa.y = pack_h2(acc[2][t].x, acc[3][t].x);
        wa.z = pack_h2(acc[4][t].x, acc[5][t].x);
        wa.w = pack_h2(acc[0][t].y, acc[1][t].y);
        wb.x = pack_h2(acc[2][t].y, acc[3][t].y);
        wb.y = pack_h2(acc[4][t].y, acc[5][t].y);
        wb.z = pack_h2(acc[0][t].z, acc[1][t].z);
        wb.w = pack_h2(acc[2][t].z, acc[3][t].z);
        wc.x = pack_h2(acc[4][t].z, acc[5][t].z);
        wc.y = pack_h2(acc[0][t].w, acc[1][t].w);
        wc.z = pack_h2(acc[2][t].w, acc[3][t].w);
        wc.w = pack_h2(acc[4][t].w, acc[5][t].w);
        w128[0] = wa; w128[1] = wb; w128[2] = wc;
    }

    __syncthreads();   // seg_l (cross-thread) + Bu visible

    // ---- compaction: ballot over contiguous 64-voxel spans ----
    {
        const int lane = threadIdx.x & 63;
        const int w = threadIdx.x >> 6;
        const unsigned long long below_mask = (1ull << lane) - 1ull;
        const unsigned char* s8 = (const unsigned char*)seg_l;
#pragma unroll
        for (int s = 0; s < 16; ++s) {
            const int v = ((w * 16 + s) << 6) + lane;      // row*128+x, x-consec.
            const int sv = (int)s8[v];
            const bool mt = (sv == label);
            const bool zt = !mt && (sv < 1 || sv > 8) && (((v & 7) + 1) == label);
            const bool pred = mt | zt;
            unsigned long long bal = __ballot(pred);
            int base = 0;
            if (lane == 0 && bal) base = atomicAdd(&cnt, (int)__popcll(bal));
            base = __shfl(base, 0);
            if (pred) {
                int pos = base + (int)__popcll(bal & below_mask);
                if (pos < LCAP)
                    lst[pos] = (unsigned short)(v | (zt ? 0x8000 : 0));
            }
        }
    }

    __syncthreads();   // lst + cnt visible

    // ---- phase 2: sparse x-conv + epilogue (or zero-store) ----
    const int total = cnt;
    if (total <= LCAP) {
        for (int e = threadIdx.x; e < total; e += 128) {
            int ent = lst[e];
            int v = ent & 2047, rr = v >> 7, x = v & 127;
            if (ent & 0x8000) zero_voxel(rr, x, z0, y0, out);
            else do_voxel_out(Bu, rr, x, z0, y0, out, kw);
        }
    } else {
        // adversarial-density fallback: dense masked sweep (same math)
        const unsigned char* s8 = (const unsigned char*)seg_l;
        for (int e = threadIdx.x; e < 2048; e += 128) {
            int rr = e >> 7, x = e & 127;
            int sv = (int)s8[e];
            if (sv == label)
                do_voxel_out(Bu, rr, x, z0, y0, out, kw);
            else if ((sv < 1 || sv > 8) && (((x & 7) + 1) == label))
                zero_voxel(rr, x, z0, y0, out);
        }
    }
}

__global__ __launch_bounds__(256) void seg_to_u8(const int* __restrict__ seg,
                                                 unsigned char* __restrict__ seg8) {
    const int t = blockIdx.x * 256 + threadIdx.x;          // 2048 blocks
    const int4 s = ((const int4*)seg)[t];
    ((uchar4*)seg8)[t] = make_uchar4((unsigned char)s.x, (unsigned char)s.y,
                                     (unsigned char)s.z, (unsigned char)s.w);
}

extern "C" void kernel_launch(void* const* d_in, const int* in_sizes, int n_in,
                              void* d_out, int out_size, void* d_ws, size_t ws_size,
                              hipStream_t stream) {
    const int* seg = (const int*)d_in[0];
    // d_in[1] (coords) unused: math is translation-invariant.
    float* out = (float*)d_out;
    unsigned short* A = (unsigned short*)d_ws;             // f16 A planes
    const size_t AVOL = (size_t)3 * NV;                    // u16 elements/label

    Kw kw;
    double gg[KL], S = 0.0;
    for (int j = 0; j < KL; ++j) { double d = j - R; gg[j] = exp(-0.5 * d * d / 25.0); S += gg[j]; }
    for (int j = 0; j < KL; ++j) {
        double gn = gg[j] / S, d = j - R;
        kw.k0[j] = (float)gn;
        kw.k1[j] = (float)(-d * gn);   // conv kernel k1 evaluated at (Z - t) = -d
        kw.k2[j] = (float)(d * d * gn);
    }

    // No memset: every output voxel is written exactly once across labels.

    const size_t need_all = 8 * AVOL * sizeof(unsigned short) + NV;  // A_all + seg8
    const size_t need_one = AVOL * sizeof(unsigned short) + NV;

    if (ws_size >= need_all) {
        // 3-dispatch path: labels batched in blockIdx.y, tile-major in x.
        unsigned char* seg8 = (unsigned char*)d_ws + 8 * AVOL * sizeof(unsigned short);
        seg_to_u8<<<dim3(2048), dim3(256), 0, stream>>>(seg, seg8);
        pass_z_t<unsigned char><<<dim3(512, 8), dim3(256), 0, stream>>>(
            seg8, A, 1, AVOL, kw);
        pass_yx<unsigned char><<<dim3(1024, 8), dim3(128), 0, stream>>>(
            A, seg8, out, 1, AVOL, kw);
    } else if (ws_size >= need_one) {
        unsigned char* seg8 = (unsigned char*)d_ws + AVOL * sizeof(unsigned short);
        seg_to_u8<<<dim3(2048), dim3(256), 0, stream>>>(seg, seg8);
        for (int label = 1; label <= 8; ++label) {
            pass_z_t<unsigned char><<<dim3(512, 1), dim3(256), 0, stream>>>(
                seg8, A, label, 0, kw);
            pass_yx<unsigned char><<<dim3(1024, 1), dim3(128), 0, stream>>>(
                A, seg8, out, label, 0, kw);
        }
    } else {
        for (int label = 1; label <= 8; ++label) {
            pass_z_t<int><<<dim3(512, 1), dim3(256), 0, stream>>>(
                seg, A, label, 0, kw);
            pass_yx<int><<<dim3(1024, 1), dim3(128), 0, stream>>>(
                A, seg, out, label, 0, kw);
        }
    }
}